// Round 3
// baseline (8011.434 us; speedup 1.0000x reference)
//
#include <hip/hip_runtime.h>
#include <math.h>

#define NB 64
#define SEQ 320
#define DMODEL 256
#define NTOK (NB * SEQ)   // 20480

// ---------------- helpers ----------------

__device__ __forceinline__ float gelu_exact(float v) {
    return 0.5f * v * (1.0f + erff(v * 0.7071067811865476f));
}

// 2D sincos positional encoding, dim=256, half=128, pairs (sin,cos)
__device__ __forceinline__ float pos2d_val(int yi, int xi, int d) {
    float coord = (float)((d < 128) ? yi : xi);
    int dd = d & 127;
    int i = dd >> 1;
    // freq = 10000^(-2i/128) = exp(-ln(10000)/64 * i)
    float freq = expf(-0.14391156831212787f * (float)i);
    float ang = coord * freq;
    return (dd & 1) ? cosf(ang) : sinf(ang);
}

// ---------------- kernels ----------------

// out = h_map (full copy), float4 grid-stride
__global__ __launch_bounds__(256) void copy_kernel(const float4* __restrict__ src,
                                                   float4* __restrict__ dst, int n4) {
    int i = blockIdx.x * 256 + threadIdx.x;
    int stride = gridDim.x * 256;
    for (; i < n4; i += stride) dst[i] = src[i];
}

// x[b, j, :] = h_map[b, idx[j], :] + pos2d(33x33)[idx[j]]   (tokens 0..255)
__global__ __launch_bounds__(256) void build_cv_kernel(const float* __restrict__ h_map,
                                                       const int* __restrict__ idx,
                                                       float* __restrict__ x) {
    int b = blockIdx.x >> 8;
    int j = blockIdx.x & 255;
    int d = threadIdx.x;
    int t = idx[j];
    int yi = t / 33, xi = t - yi * 33;
    float v = h_map[((size_t)b * 1089 + t) * DMODEL + d];
    x[((size_t)b * SEQ + j) * DMODEL + d] = v + pos2d_val(yi, xi, d);
}

// x[b, 256+tok, :] = patch_embed + patch_b + pos2d(8x8)[tok]
__global__ __launch_bounds__(256) void patch_kernel(const float* __restrict__ frame,
                                                    const float* __restrict__ pw,
                                                    const float* __restrict__ pb,
                                                    float* __restrict__ x) {
    int b = blockIdx.x >> 6;
    int tok = blockIdx.x & 63;
    int hh = tok >> 3, ww = tok & 7;
    __shared__ float pf[768];
    int tid = threadIdx.x;
    const float* fb = frame + (size_t)b * 3 * 128 * 128;
    for (int k = tid; k < 768; k += 256) {
        int c = k >> 8, rem = k & 255, p = rem >> 4, q = rem & 15;
        pf[k] = fb[c * 16384 + (hh * 16 + p) * 128 + (ww * 16 + q)];
    }
    __syncthreads();
    int d = tid;
    float acc = pb[d];
    const float* wrow = pw + (size_t)d * 768;
#pragma unroll 4
    for (int k = 0; k < 768; ++k) acc += pf[k] * wrow[k];
    x[((size_t)b * SEQ + 256 + tok) * DMODEL + d] = acc + pos2d_val(hh, ww, d);
}

// row LayerNorm: one block (256 thr) per row, D=256
__global__ __launch_bounds__(256) void ln_kernel(const float* __restrict__ in,
                                                 float* __restrict__ outp,
                                                 const float* __restrict__ g,
                                                 const float* __restrict__ bta) {
    int r = blockIdx.x;
    int d = threadIdx.x;
    float v = in[(size_t)r * DMODEL + d];
    float s = v, ss = v * v;
#pragma unroll
    for (int off = 32; off; off >>= 1) {
        s  += __shfl_down(s, off);
        ss += __shfl_down(ss, off);
    }
    __shared__ float red[8];
    int wid = d >> 6, lane = d & 63;
    if (lane == 0) { red[wid] = s; red[4 + wid] = ss; }
    __syncthreads();
    float S  = red[0] + red[1] + red[2] + red[3];
    float SS = red[4] + red[5] + red[6] + red[7];
    float mu = S * (1.0f / 256.0f);
    float var = SS * (1.0f / 256.0f) - mu * mu;
    float rstd = rsqrtf(var + 1e-5f);
    outp[(size_t)r * DMODEL + d] = (v - mu) * rstd * g[d] + bta[d];
}

// C[M,N] = act(A[M,K] @ W[N,K]^T + bias[N]) (+ res[M,N]); 64x64 tile, BK=16
template <int ACT, int RES>
__global__ __launch_bounds__(256) void gemm_tn(const float* __restrict__ A,
                                               const float* __restrict__ W,
                                               const float* __restrict__ bias,
                                               const float* __restrict__ res,
                                               float* __restrict__ C,
                                               int M, int N, int K) {
    __shared__ float As[16][65];
    __shared__ float Bs[16][65];
    int bm = blockIdx.y * 64, bn = blockIdx.x * 64;
    int tid = threadIdx.x;
    int tm = (tid >> 4) << 2;
    int tn = (tid & 15) << 2;
    float acc[4][4] = {{0}};
    int lrow = tid >> 2;
    int lcol = (tid & 3) << 2;
    for (int k0 = 0; k0 < K; k0 += 16) {
        float4 a = *(const float4*)&A[(size_t)(bm + lrow) * K + k0 + lcol];
        float4 w = *(const float4*)&W[(size_t)(bn + lrow) * K + k0 + lcol];
        As[lcol + 0][lrow] = a.x; As[lcol + 1][lrow] = a.y;
        As[lcol + 2][lrow] = a.z; As[lcol + 3][lrow] = a.w;
        Bs[lcol + 0][lrow] = w.x; Bs[lcol + 1][lrow] = w.y;
        Bs[lcol + 2][lrow] = w.z; Bs[lcol + 3][lrow] = w.w;
        __syncthreads();
#pragma unroll
        for (int kk = 0; kk < 16; ++kk) {
            float av[4], bv[4];
#pragma unroll
            for (int i = 0; i < 4; ++i) av[i] = As[kk][tm + i];
#pragma unroll
            for (int j = 0; j < 4; ++j) bv[j] = Bs[kk][tn + j];
#pragma unroll
            for (int i = 0; i < 4; ++i)
#pragma unroll
                for (int j = 0; j < 4; ++j) acc[i][j] += av[i] * bv[j];
        }
        __syncthreads();
    }
#pragma unroll
    for (int i = 0; i < 4; ++i) {
#pragma unroll
        for (int j = 0; j < 4; ++j) {
            float val = acc[i][j] + bias[bn + tn + j];
            if (ACT == 1) val = gelu_exact(val);
            if (RES) val += res[(size_t)(bm + tm + i) * N + bn + tn + j];
            C[(size_t)(bm + tm + i) * N + bn + tn + j] = val;
        }
    }
}

// flash-style attention: one block per (b, head), 320 threads = one q-row each
__global__ __launch_bounds__(320) void attn_kernel(const float* __restrict__ qkv,
                                                   float* __restrict__ o) {
    int b = blockIdx.x >> 3;
    int h = blockIdx.x & 7;
    int r = threadIdx.x;
    const float* base = qkv + (size_t)b * SEQ * 768;
    const float* qrow = base + (size_t)r * 768 + h * 32;
    float q[32];
#pragma unroll
    for (int d = 0; d < 32; ++d) q[d] = qrow[d] * 0.17677669529663687f;

    __shared__ float Ks[16][32];
    __shared__ float Vs[16][32];
    float m = -INFINITY, ssum = 0.0f;
    float acc[32];
#pragma unroll
    for (int d = 0; d < 32; ++d) acc[d] = 0.0f;

    for (int k0 = 0; k0 < SEQ; k0 += 16) {
        // stage 16 K rows and 16 V rows (threads 0..255)
        int t = threadIdx.x;
        if (t < 128) {
            int row = t >> 3, c4 = (t & 7) << 2;
            float4 kv = *(const float4*)&base[(size_t)(k0 + row) * 768 + 256 + h * 32 + c4];
            Ks[row][c4] = kv.x; Ks[row][c4 + 1] = kv.y; Ks[row][c4 + 2] = kv.z; Ks[row][c4 + 3] = kv.w;
        } else if (t < 256) {
            int t2 = t - 128;
            int row = t2 >> 3, c4 = (t2 & 7) << 2;
            float4 vv = *(const float4*)&base[(size_t)(k0 + row) * 768 + 512 + h * 32 + c4];
            Vs[row][c4] = vv.x; Vs[row][c4 + 1] = vv.y; Vs[row][c4 + 2] = vv.z; Vs[row][c4 + 3] = vv.w;
        }
        __syncthreads();

        float sc[16];
        float cm = -INFINITY;
#pragma unroll
        for (int kk = 0; kk < 16; ++kk) {
            float dot = 0.0f;
#pragma unroll
            for (int d = 0; d < 32; ++d) dot += q[d] * Ks[kk][d];
            sc[kk] = dot;
            cm = fmaxf(cm, dot);
        }
        float nm = fmaxf(m, cm);
        float corr = expf(m - nm);
        ssum *= corr;
#pragma unroll
        for (int d = 0; d < 32; ++d) acc[d] *= corr;
#pragma unroll
        for (int kk = 0; kk < 16; ++kk) {
            float w = expf(sc[kk] - nm);
            ssum += w;
#pragma unroll
            for (int d = 0; d < 32; ++d) acc[d] += w * Vs[kk][d];
        }
        m = nm;
        __syncthreads();
    }
    float inv = 1.0f / ssum;
    float* orow = o + ((size_t)b * SEQ + r) * DMODEL + h * 32;
#pragma unroll
    for (int d = 0; d < 32; ++d) orow[d] = acc[d] * inv;
}

// gate + scatter-write: one block per (b, j)
__global__ __launch_bounds__(256) void gate_kernel(const float* __restrict__ xf,
                                                   const float* __restrict__ h_map,
                                                   const int* __restrict__ idx,
                                                   const float* __restrict__ gw,
                                                   const float* __restrict__ gb,
                                                   float* __restrict__ out) {
    int b = blockIdx.x >> 8;
    int j = blockIdx.x & 255;
    int d = threadIdx.x;
    __shared__ float cv[256], nv[256];
    int t = idx[j];
    float hv = h_map[((size_t)b * 1089 + t) * DMODEL + d];
    float nvv = xf[((size_t)b * SEQ + j) * DMODEL + d];
    cv[d] = hv;
    nv[d] = nvv;
    __syncthreads();
    float a = gb[d];
    const float* grow = gw + (size_t)d * 512;
#pragma unroll 4
    for (int k = 0; k < 256; ++k) a += grow[k] * cv[k] + grow[256 + k] * nv[k];
    float g = 1.0f / (1.0f + expf(-a));
    out[((size_t)b * 1089 + t) * DMODEL + d] = (1.0f - g) * hv + g * nvv;
}

// ---------------- launch ----------------

extern "C" void kernel_launch(void* const* d_in, const int* in_sizes, int n_in,
                              void* d_out, int out_size, void* d_ws, size_t ws_size,
                              hipStream_t stream) {
    const float* h_map  = (const float*)d_in[0];
    const float* frame  = (const float*)d_in[1];
    const int*   idx    = (const int*)d_in[2];
    const float* Wqkv   = (const float*)d_in[3];
    const float* bqkv   = (const float*)d_in[4];
    const float* Wo     = (const float*)d_in[5];
    const float* bo     = (const float*)d_in[6];
    const float* ln1g   = (const float*)d_in[7];
    const float* ln1b   = (const float*)d_in[8];
    const float* W1     = (const float*)d_in[9];
    const float* b1     = (const float*)d_in[10];
    const float* W2     = (const float*)d_in[11];
    const float* b2     = (const float*)d_in[12];
    const float* ln2g   = (const float*)d_in[13];
    const float* ln2b   = (const float*)d_in[14];
    const float* nfg    = (const float*)d_in[15];
    const float* nfb    = (const float*)d_in[16];
    const float* patchw = (const float*)d_in[17];
    const float* patchb = (const float*)d_in[18];
    const float* gatew  = (const float*)d_in[19];
    const float* gateb  = (const float*)d_in[20];
    float* out = (float*)d_out;

    float* x   = (float*)d_ws;                      // NTOK*256
    float* y   = x + (size_t)NTOK * 256;            // NTOK*256
    float* big = y + (size_t)NTOK * 256;            // NTOK*1024 (qkv / mlp hidden)

    // out = h_map
    int n4 = (NB * 1089 * DMODEL) / 4;
    hipLaunchKernelGGL(copy_kernel, dim3(2048), dim3(256), 0, stream,
                       (const float4*)h_map, (float4*)out, n4);

    // build x
    hipLaunchKernelGGL(build_cv_kernel, dim3(NB * 256), dim3(256), 0, stream, h_map, idx, x);
    hipLaunchKernelGGL(patch_kernel, dim3(NB * 64), dim3(256), 0, stream, frame, patchw, patchb, x);

    for (int l = 0; l < 6; ++l) {
        const float* wqkv_l = Wqkv + (size_t)l * 768 * 256;
        const float* bqkv_l = bqkv + (size_t)l * 768;
        const float* wo_l   = Wo   + (size_t)l * 256 * 256;
        const float* bo_l   = bo   + (size_t)l * 256;
        const float* w1_l   = W1   + (size_t)l * 1024 * 256;
        const float* b1_l   = b1   + (size_t)l * 1024;
        const float* w2_l   = W2   + (size_t)l * 256 * 1024;
        const float* b2_l   = b2   + (size_t)l * 256;

        // y = LN1(x)
        hipLaunchKernelGGL(ln_kernel, dim3(NTOK), dim3(256), 0, stream,
                           x, y, ln1g + l * 256, ln1b + l * 256);
        // big = y @ Wqkv^T + bqkv   (M=NTOK, N=768, K=256)
        hipLaunchKernelGGL((gemm_tn<0, 0>), dim3(768 / 64, NTOK / 64), dim3(256), 0, stream,
                           y, wqkv_l, bqkv_l, nullptr, big, NTOK, 768, 256);
        // y = attention(big)
        hipLaunchKernelGGL(attn_kernel, dim3(NB * 8), dim3(320), 0, stream, big, y);
        // x = x + y @ Wo^T + bo
        hipLaunchKernelGGL((gemm_tn<0, 1>), dim3(256 / 64, NTOK / 64), dim3(256), 0, stream,
                           y, wo_l, bo_l, x, x, NTOK, 256, 256);
        // y = LN2(x)
        hipLaunchKernelGGL(ln_kernel, dim3(NTOK), dim3(256), 0, stream,
                           x, y, ln2g + l * 256, ln2b + l * 256);
        // big = gelu(y @ W1^T + b1)  (N=1024)
        hipLaunchKernelGGL((gemm_tn<1, 0>), dim3(1024 / 64, NTOK / 64), dim3(256), 0, stream,
                           y, w1_l, b1_l, nullptr, big, NTOK, 1024, 256);
        // x = x + big @ W2^T + b2   (K=1024)
        hipLaunchKernelGGL((gemm_tn<0, 1>), dim3(256 / 64, NTOK / 64), dim3(256), 0, stream,
                           big, w2_l, b2_l, x, x, NTOK, 256, 1024);
    }

    // y = final LN(x)
    hipLaunchKernelGGL(ln_kernel, dim3(NTOK), dim3(256), 0, stream, x, y, nfg, nfb);

    // gate + scatter into out
    hipLaunchKernelGGL(gate_kernel, dim3(NB * 256), dim3(256), 0, stream,
                       y, h_map, idx, gatew, gateb, out);
}

// Round 10
// 2822.101 us; speedup vs baseline: 2.8388x; 2.8388x over previous
//
#include <hip/hip_runtime.h>
#include <math.h>

#define NB 64
#define SEQ 320
#define NCV 256
#define NTOK (NB * SEQ)    // 20480
#define NGROW (NB * NCV)   // 16384

typedef unsigned short u16;
typedef __attribute__((ext_vector_type(8))) short short8;
typedef __attribute__((ext_vector_type(4))) float f32x4;

// ---------------- scalar helpers ----------------

__device__ __forceinline__ float bf2f(u16 u) {
    union { unsigned int i; float f; } v; v.i = ((unsigned int)u) << 16; return v.f;
}
__device__ __forceinline__ u16 f2bf(float f) {
    union { float f; unsigned int i; } v; v.f = f;
    unsigned int lsb = (v.i >> 16) & 1u;
    return (u16)((v.i + 0x7fffu + lsb) >> 16);   // RNE; inputs are finite
}
__device__ __forceinline__ float gelu_exact(float v) {
    return 0.5f * v * (1.0f + erff(v * 0.7071067811865476f));
}
__device__ __forceinline__ float pos2d_val(int yi, int xi, int d) {
    float coord = (float)((d < 128) ? yi : xi);
    int dd = d & 127;
    int i = dd >> 1;
    float freq = expf(-0.14391156831212787f * (float)i);  // 10000^(-2i/128)
    float ang = coord * freq;
    return (dd & 1) ? cosf(ang) : sinf(ang);
}

__device__ __forceinline__ void gload16(const void* g, void* l) {
    __builtin_amdgcn_global_load_lds((const __attribute__((address_space(1))) unsigned int*)g,
                                     (__attribute__((address_space(3))) unsigned int*)l,
                                     16, 0, 0);
}

// ---------------- small kernels ----------------

__global__ __launch_bounds__(256) void conv_bf16_kernel(const float* __restrict__ in,
                                                        u16* __restrict__ outp, int n) {
    int i = blockIdx.x * 256 + threadIdx.x;
    int stride = gridDim.x * 256;
    for (; i < n; i += stride) outp[i] = f2bf(in[i]);
}

__global__ __launch_bounds__(256) void copy_kernel(const float4* __restrict__ src,
                                                   float4* __restrict__ dst, int n4) {
    int i = blockIdx.x * 256 + threadIdx.x;
    int stride = gridDim.x * 256;
    for (; i < n4; i += stride) dst[i] = src[i];
}

// x[b,j,:] = h_map[b,idx[j],:] + pos ;  Acat[b*256+j][0..255] = bf16(h_map val)
__global__ __launch_bounds__(256) void build_cv_kernel(const float* __restrict__ h_map,
                                                       const int* __restrict__ idx,
                                                       float* __restrict__ x,
                                                       u16* __restrict__ Acat) {
    int b = blockIdx.x >> 8;
    int j = blockIdx.x & 255;
    int d = threadIdx.x;
    int t = idx[j];
    int yi = t / 33, xi = t - yi * 33;
    float v = h_map[((size_t)b * 1089 + t) * 256 + d];
    x[((size_t)b * SEQ + j) * 256 + d] = v + pos2d_val(yi, xi, d);
    Acat[((size_t)b * NCV + j) * 512 + d] = f2bf(v);
}

__global__ __launch_bounds__(256) void patch_kernel(const float* __restrict__ frame,
                                                    const float* __restrict__ pw,
                                                    const float* __restrict__ pb,
                                                    float* __restrict__ x) {
    int b = blockIdx.x >> 6;
    int tok = blockIdx.x & 63;
    int hh = tok >> 3, ww = tok & 7;
    __shared__ float pf[768];
    int tid = threadIdx.x;
    const float* fb = frame + (size_t)b * 3 * 128 * 128;
    for (int k = tid; k < 768; k += 256) {
        int c = k >> 8, rem = k & 255, p = rem >> 4, q = rem & 15;
        pf[k] = fb[c * 16384 + (hh * 16 + p) * 128 + (ww * 16 + q)];
    }
    __syncthreads();
    int d = tid;
    float acc = pb[d];
    const float* wrow = pw + (size_t)d * 768;
#pragma unroll 4
    for (int k = 0; k < 768; ++k) acc += pf[k] * wrow[k];
    x[((size_t)b * SEQ + 256 + tok) * 256 + d] = acc + pos2d_val(hh, ww, d);
}

// LN reduce helper: returns (mu, rstd) for value v across the 256-thread block
__device__ __forceinline__ void ln_stats(float v, float& mu, float& rstd) {
    float s = v, ss = v * v;
#pragma unroll
    for (int off = 32; off; off >>= 1) {
        s  += __shfl_down(s, off);
        ss += __shfl_down(ss, off);
    }
    __shared__ float red[8];
    int wid = threadIdx.x >> 6, lane = threadIdx.x & 63;
    if (lane == 0) { red[wid] = s; red[4 + wid] = ss; }
    __syncthreads();
    float S  = red[0] + red[1] + red[2] + red[3];
    float SS = red[4] + red[5] + red[6] + red[7];
    mu = S * (1.0f / 256.0f);
    float var = SS * (1.0f / 256.0f) - mu * mu;
    rstd = rsqrtf(var + 1e-5f);
}

// LN over all NTOK rows, bf16 out (stride 256)
__global__ __launch_bounds__(256) void ln_bf16_kernel(const float* __restrict__ in,
                                                      u16* __restrict__ outp,
                                                      const float* __restrict__ g,
                                                      const float* __restrict__ bta) {
    int r = blockIdx.x, d = threadIdx.x;
    float v = in[(size_t)r * 256 + d];
    float mu, rstd; ln_stats(v, mu, rstd);
    outp[(size_t)r * 256 + d] = f2bf((v - mu) * rstd * g[d] + bta[d]);
}

// final LN: only carrier rows (b, j<256); writes bf16 into Acat[:, 256:512]
__global__ __launch_bounds__(256) void ln_final_kernel(const float* __restrict__ in,
                                                       u16* __restrict__ Acat,
                                                       const float* __restrict__ g,
                                                       const float* __restrict__ bta) {
    int r = blockIdx.x;                 // 0..16383
    int b = r >> 8, j = r & 255, d = threadIdx.x;
    float v = in[((size_t)b * SEQ + j) * 256 + d];
    float mu, rstd; ln_stats(v, mu, rstd);
    Acat[(size_t)r * 512 + 256 + d] = f2bf((v - mu) * rstd * g[d] + bta[d]);
}

// ---------------- bf16 MFMA GEMM ----------------
// C[M,N] = epi(A[M,K](bf16) @ W[N,K](bf16)^T + bias)   [+ res f32]
// 128x128 tile, BK=32, 256 thr = 4 waves (2x2 of 64x64), double-buffered LDS.
// LDS layout [kb][row][8] -> frag read is ds_read_b128, lanes 0-15 contiguous.
// ACT: 0=none 1=gelu 2=sigmoid ; OUTBF: write bf16 instead of f32.
template <int ACT, int RES, int OUTBF>
__global__ __launch_bounds__(256) void gemm_mfma(const u16* __restrict__ A,
                                                 const u16* __restrict__ W,
                                                 const float* __restrict__ bias,
                                                 const float* __restrict__ res,
                                                 void* __restrict__ Cptr,
                                                 int M, int N, int K) {
    __shared__ u16 lA[2][4][128][8];
    __shared__ u16 lB[2][4][128][8];
    int tid = threadIdx.x;
    int w = tid >> 6, lane = tid & 63;
    int bm = blockIdx.y * 128, bn = blockIdx.x * 128;
    int wr = w >> 1, wc = w & 1;     // 2x2 waves of 64x64

    f32x4 acc[4][4];
#pragma unroll
    for (int r = 0; r < 4; ++r)
#pragma unroll
        for (int c = 0; c < 4; ++c) acc[r][c] = (f32x4){0.f, 0.f, 0.f, 0.f};

    int nt = K / 32;
    // wave w stages kb=w, both row-halves, for A and B
    auto stage = [&](int buf, int t) {
        int k0 = t * 32;
#pragma unroll
        for (int jj = 0; jj < 2; ++jj) {
            int r0 = jj * 64;
            gload16(&A[(size_t)(bm + r0 + lane) * K + k0 + w * 8], &lA[buf][w][r0][0]);
            gload16(&W[(size_t)(bn + r0 + lane) * K + k0 + w * 8], &lB[buf][w][r0][0]);
        }
    };

    stage(0, 0);
    __syncthreads();
    int cur = 0;
    int kb = lane >> 4, rr = lane & 15;
    for (int t = 0; t < nt; ++t) {
        if (t + 1 < nt) stage(cur ^ 1, t + 1);
        short8 af[4], bfv[4];
#pragma unroll
        for (int r = 0; r < 4; ++r)
            af[r] = *(const short8*)&lA[cur][kb][wr * 64 + r * 16 + rr][0];
#pragma unroll
        for (int c = 0; c < 4; ++c)
            bfv[c] = *(const short8*)&lB[cur][kb][wc * 64 + c * 16 + rr][0];
#pragma unroll
        for (int r = 0; r < 4; ++r)
#pragma unroll
            for (int c = 0; c < 4; ++c)
                acc[r][c] = __builtin_amdgcn_mfma_f32_16x16x32_bf16(af[r], bfv[c], acc[r][c], 0, 0, 0);
        __syncthreads();
        cur ^= 1;
    }

    float* Cf = (float*)Cptr;
    u16*   Cb = (u16*)Cptr;
#pragma unroll
    for (int c = 0; c < 4; ++c) {
        int col = bn + wc * 64 + c * 16 + (lane & 15);
        float bia = bias[col];
#pragma unroll
        for (int r = 0; r < 4; ++r) {
#pragma unroll
            for (int j = 0; j < 4; ++j) {
                int row = bm + wr * 64 + r * 16 + (lane >> 4) * 4 + j;
                float v = acc[r][c][j] + bia;
                if (ACT == 1) v = gelu_exact(v);
                if (ACT == 2) v = 1.0f / (1.0f + expf(-v));
                if (RES) v += res[(size_t)row * N + col];
                if (OUTBF) Cb[(size_t)row * N + col] = f2bf(v);
                else       Cf[(size_t)row * N + col] = v;
            }
        }
    }
}

// ---------------- attention (bf16 in/out, fp32 inside) ----------------

__global__ __launch_bounds__(320) void attn_kernel(const u16* __restrict__ qkv,
                                                   u16* __restrict__ o) {
    int b = blockIdx.x >> 3;
    int h = blockIdx.x & 7;
    int r = threadIdx.x;
    const u16* base = qkv + (size_t)b * SEQ * 768;
    const u16* qrow = base + (size_t)r * 768 + h * 32;
    float q[32];
#pragma unroll
    for (int d = 0; d < 32; ++d) q[d] = bf2f(qrow[d]) * 0.17677669529663687f;

    __shared__ float Ks[16][32];
    __shared__ float Vs[16][32];
    float m = -INFINITY, ssum = 0.0f;
    float acc[32];
#pragma unroll
    for (int d = 0; d < 32; ++d) acc[d] = 0.0f;

    for (int k0 = 0; k0 < SEQ; k0 += 16) {
        int t = threadIdx.x;
        if (t < 128) {
            int row = t >> 3, c4 = (t & 7) << 2;
            ushort4 kv = *(const ushort4*)&base[(size_t)(k0 + row) * 768 + 256 + h * 32 + c4];
            Ks[row][c4] = bf2f(kv.x); Ks[row][c4 + 1] = bf2f(kv.y);
            Ks[row][c4 + 2] = bf2f(kv.z); Ks[row][c4 + 3] = bf2f(kv.w);
        } else if (t < 256) {
            int t2 = t - 128;
            int row = t2 >> 3, c4 = (t2 & 7) << 2;
            ushort4 vv = *(const ushort4*)&base[(size_t)(k0 + row) * 768 + 512 + h * 32 + c4];
            Vs[row][c4] = bf2f(vv.x); Vs[row][c4 + 1] = bf2f(vv.y);
            Vs[row][c4 + 2] = bf2f(vv.z); Vs[row][c4 + 3] = bf2f(vv.w);
        }
        __syncthreads();

        float sc[16];
        float cm = -INFINITY;
#pragma unroll
        for (int kk = 0; kk < 16; ++kk) {
            float dot = 0.0f;
#pragma unroll
            for (int d = 0; d < 32; ++d) dot += q[d] * Ks[kk][d];
            sc[kk] = dot;
            cm = fmaxf(cm, dot);
        }
        float nm = fmaxf(m, cm);
        float corr = expf(m - nm);
        ssum *= corr;
#pragma unroll
        for (int d = 0; d < 32; ++d) acc[d] *= corr;
#pragma unroll
        for (int kk = 0; kk < 16; ++kk) {
            float wgt = expf(sc[kk] - nm);
            ssum += wgt;
#pragma unroll
            for (int d = 0; d < 32; ++d) acc[d] += wgt * Vs[kk][d];
        }
        m = nm;
        __syncthreads();
    }
    float inv = 1.0f / ssum;
    u16* orow = o + ((size_t)b * SEQ + r) * 256 + h * 32;
#pragma unroll
    for (int d = 0; d < 32; ++d) orow[d] = f2bf(acc[d] * inv);
}

// ---------------- gate blend + scatter ----------------

__global__ __launch_bounds__(256) void gate_apply_kernel(const float* __restrict__ g,
                                                         const float* __restrict__ h_map,
                                                         const int* __restrict__ idx,
                                                         const u16* __restrict__ Acat,
                                                         float* __restrict__ outp) {
    int b = blockIdx.x >> 8;
    int j = blockIdx.x & 255;
    int d = threadIdx.x;
    int t = idx[j];
    size_t row = (size_t)b * NCV + j;
    float gv = g[row * 256 + d];
    float hv = h_map[((size_t)b * 1089 + t) * 256 + d];
    float nv = bf2f(Acat[row * 512 + 256 + d]);
    outp[((size_t)b * 1089 + t) * 256 + d] = (1.0f - gv) * hv + gv * nv;
}

// ---------------- launch ----------------

extern "C" void kernel_launch(void* const* d_in, const int* in_sizes, int n_in,
                              void* d_out, int out_size, void* d_ws, size_t ws_size,
                              hipStream_t stream) {
    const float* h_map  = (const float*)d_in[0];
    const float* frame  = (const float*)d_in[1];
    const int*   idx    = (const int*)d_in[2];
    const float* Wqkv   = (const float*)d_in[3];
    const float* bqkv   = (const float*)d_in[4];
    const float* Wo     = (const float*)d_in[5];
    const float* bo     = (const float*)d_in[6];
    const float* ln1g   = (const float*)d_in[7];
    const float* ln1b   = (const float*)d_in[8];
    const float* W1     = (const float*)d_in[9];
    const float* b1     = (const float*)d_in[10];
    const float* W2     = (const float*)d_in[11];
    const float* b2     = (const float*)d_in[12];
    const float* ln2g   = (const float*)d_in[13];
    const float* ln2b   = (const float*)d_in[14];
    const float* nfg    = (const float*)d_in[15];
    const float* nfb    = (const float*)d_in[16];
    const float* patchw = (const float*)d_in[17];
    const float* patchb = (const float*)d_in[18];
    const float* gatew  = (const float*)d_in[19];
    const float* gateb  = (const float*)d_in[20];
    float* out = (float*)d_out;

    char* ws = (char*)d_ws;
    size_t off = 0;
    float* x     = (float*)(ws + off); off += (size_t)NTOK * 256 * 4;   // residual stream
    u16*   xbf   = (u16*)(ws + off);   off += (size_t)NTOK * 256 * 2;   // LN out / attn out
    u16*   bigbf = (u16*)(ws + off);   off += (size_t)NTOK * 1024 * 2;  // qkv / mlp hidden
    u16*   Acat  = (u16*)(ws + off);   off += (size_t)NGROW * 512 * 2;  // [h_cv | ln_f]
    float* gbuf  = (float*)(ws + off); off += (size_t)NGROW * 256 * 4;  // sigmoid gates
    u16* wqkvbf  = (u16*)(ws + off);   off += (size_t)6 * 768 * 256 * 2;
    u16* wobf    = (u16*)(ws + off);   off += (size_t)6 * 256 * 256 * 2;
    u16* w1bf    = (u16*)(ws + off);   off += (size_t)6 * 1024 * 256 * 2;
    u16* w2bf    = (u16*)(ws + off);   off += (size_t)6 * 256 * 1024 * 2;
    u16* gwbf    = (u16*)(ws + off);   off += (size_t)256 * 512 * 2;

    // weights -> bf16
    hipLaunchKernelGGL(conv_bf16_kernel, dim3(1024), dim3(256), 0, stream, Wqkv, wqkvbf, 6 * 768 * 256);
    hipLaunchKernelGGL(conv_bf16_kernel, dim3(512),  dim3(256), 0, stream, Wo,   wobf,   6 * 256 * 256);
    hipLaunchKernelGGL(conv_bf16_kernel, dim3(1024), dim3(256), 0, stream, W1,   w1bf,   6 * 1024 * 256);
    hipLaunchKernelGGL(conv_bf16_kernel, dim3(1024), dim3(256), 0, stream, W2,   w2bf,   6 * 256 * 1024);
    hipLaunchKernelGGL(conv_bf16_kernel, dim3(128),  dim3(256), 0, stream, gatew, gwbf,  256 * 512);

    // out = h_map ; build x ; Acat left half
    int n4 = (NB * 1089 * 256) / 4;
    hipLaunchKernelGGL(copy_kernel, dim3(2048), dim3(256), 0, stream,
                       (const float4*)h_map, (float4*)out, n4);
    hipLaunchKernelGGL(build_cv_kernel, dim3(NB * 256), dim3(256), 0, stream, h_map, idx, x, Acat);
    hipLaunchKernelGGL(patch_kernel, dim3(NB * 64), dim3(256), 0, stream, frame, patchw, patchb, x);

    for (int l = 0; l < 6; ++l) {
        const u16* wqkv_l = wqkvbf + (size_t)l * 768 * 256;
        const u16* wo_l   = wobf   + (size_t)l * 256 * 256;
        const u16* w1_l   = w1bf   + (size_t)l * 1024 * 256;
        const u16* w2_l   = w2bf   + (size_t)l * 256 * 1024;

        hipLaunchKernelGGL(ln_bf16_kernel, dim3(NTOK), dim3(256), 0, stream,
                           x, xbf, ln1g + l * 256, ln1b + l * 256);
        hipLaunchKernelGGL((gemm_mfma<0, 0, 1>), dim3(6, 160), dim3(256), 0, stream,
                           xbf, wqkv_l, bqkv + l * 768, nullptr, bigbf, NTOK, 768, 256);
        hipLaunchKernelGGL(attn_kernel, dim3(NB * 8), dim3(320), 0, stream, bigbf, xbf);
        hipLaunchKernelGGL((gemm_mfma<0, 1, 0>), dim3(2, 160), dim3(256), 0, stream,
                           xbf, wo_l, bo + l * 256, x, x, NTOK, 256, 256);
        hipLaunchKernelGGL(ln_bf16_kernel, dim3(NTOK), dim3(256), 0, stream,
                           x, xbf, ln2g + l * 256, ln2b + l * 256);
        hipLaunchKernelGGL((gemm_mfma<1, 0, 1>), dim3(8, 160), dim3(256), 0, stream,
                           xbf, w1_l, b1 + l * 1024, nullptr, bigbf, NTOK, 1024, 256);
        hipLaunchKernelGGL((gemm_mfma<0, 1, 0>), dim3(2, 160), dim3(256), 0, stream,
                           bigbf, w2_l, b2 + l * 256, x, x, NTOK, 256, 1024);
    }

    // final LN (carrier rows only) -> Acat right half
    hipLaunchKernelGGL(ln_final_kernel, dim3(NGROW), dim3(256), 0, stream, x, Acat, nfg, nfb);
    // gate GEMM: g = sigmoid(Acat @ gate_w^T + gate_b)
    hipLaunchKernelGGL((gemm_mfma<2, 0, 0>), dim3(2, 128), dim3(256), 0, stream,
                       Acat, gwbf, gateb, nullptr, gbuf, NGROW, 256, 512);
    // blend + scatter
    hipLaunchKernelGGL(gate_apply_kernel, dim3(NB * 256), dim3(256), 0, stream,
                       gbuf, h_map, idx, Acat, out);
}

// Round 12
// 2150.064 us; speedup vs baseline: 3.7261x; 1.3126x over previous
//
#include <hip/hip_runtime.h>
#include <math.h>

#define NB 64
#define SEQ 320
#define NCV 256
#define NTOK (NB * SEQ)    // 20480
#define NGROW (NB * NCV)   // 16384

typedef unsigned short u16;
typedef __attribute__((ext_vector_type(8))) short short8;
typedef __attribute__((ext_vector_type(4))) float f32x4;

// ---------------- scalar helpers ----------------

__device__ __forceinline__ float bf2f(u16 u) {
    union { unsigned int i; float f; } v; v.i = ((unsigned int)u) << 16; return v.f;
}
__device__ __forceinline__ u16 f2bf(float f) {
    union { float f; unsigned int i; } v; v.f = f;
    unsigned int lsb = (v.i >> 16) & 1u;
    return (u16)((v.i + 0x7fffu + lsb) >> 16);   // RNE; inputs are finite
}
__device__ __forceinline__ float gelu_exact(float v) {
    return 0.5f * v * (1.0f + erff(v * 0.7071067811865476f));
}
__device__ __forceinline__ float pos2d_val(int yi, int xi, int d) {
    float coord = (float)((d < 128) ? yi : xi);
    int dd = d & 127;
    int i = dd >> 1;
    float freq = expf(-0.14391156831212787f * (float)i);  // 10000^(-2i/128)
    float ang = coord * freq;
    return (dd & 1) ? cosf(ang) : sinf(ang);
}

__device__ __forceinline__ void gload16(const void* g, void* l) {
    __builtin_amdgcn_global_load_lds((const __attribute__((address_space(1))) unsigned int*)g,
                                     (__attribute__((address_space(3))) unsigned int*)l,
                                     16, 0, 0);
}

// ---------------- small kernels ----------------

__global__ __launch_bounds__(256) void conv_bf16_kernel(const float* __restrict__ in,
                                                        u16* __restrict__ outp, int n) {
    int i = blockIdx.x * 256 + threadIdx.x;
    int stride = gridDim.x * 256;
    for (; i < n; i += stride) outp[i] = f2bf(in[i]);
}

__global__ __launch_bounds__(256) void copy_kernel(const float4* __restrict__ src,
                                                   float4* __restrict__ dst, int n4) {
    int i = blockIdx.x * 256 + threadIdx.x;
    int stride = gridDim.x * 256;
    for (; i < n4; i += stride) dst[i] = src[i];
}

// x[b,j,:] = h_map[b,idx[j],:] + pos ;  Acat[b*256+j][0..255] = bf16(h_map val)
__global__ __launch_bounds__(256) void build_cv_kernel(const float* __restrict__ h_map,
                                                       const int* __restrict__ idx,
                                                       float* __restrict__ x,
                                                       u16* __restrict__ Acat) {
    int b = blockIdx.x >> 8;
    int j = blockIdx.x & 255;
    int d = threadIdx.x;
    int t = idx[j];
    int yi = t / 33, xi = t - yi * 33;
    float v = h_map[((size_t)b * 1089 + t) * 256 + d];
    x[((size_t)b * SEQ + j) * 256 + d] = v + pos2d_val(yi, xi, d);
    Acat[((size_t)b * NCV + j) * 512 + d] = f2bf(v);
}

// frame -> bf16 im2col rows [b*64+tok][768], k = c*256 + p*16 + q
__global__ __launch_bounds__(256) void im2col_kernel(const float* __restrict__ frame,
                                                     u16* __restrict__ Abf) {
    int row = blockIdx.x;                 // 0..4095
    int b = row >> 6, tok = row & 63;
    int hh = tok >> 3, ww = tok & 7;
    const float* fb = frame + (size_t)b * 3 * 128 * 128;
    int tid = threadIdx.x;
#pragma unroll
    for (int kk = 0; kk < 3; ++kk) {
        int k = tid + kk * 256;
        int c = k >> 8, rem = k & 255, p = rem >> 4, q = rem & 15;
        float v = fb[c * 16384 + (hh * 16 + p) * 128 + (ww * 16 + q)];
        Abf[(size_t)row * 768 + k] = f2bf(v);
    }
}

// ptok[row][d] + pos2d -> x[b*SEQ+256+tok][d]
__global__ __launch_bounds__(256) void patch_scatter_kernel(const float* __restrict__ ptok,
                                                            float* __restrict__ x) {
    int row = blockIdx.x;                 // 0..4095
    int b = row >> 6, tok = row & 63;
    int d = threadIdx.x;
    float v = ptok[(size_t)row * 256 + d] + pos2d_val(tok >> 3, tok & 7, d);
    x[((size_t)b * SEQ + 256 + tok) * 256 + d] = v;
}

// LN reduce helper: returns (mu, rstd) for value v across the 256-thread block
__device__ __forceinline__ void ln_stats(float v, float& mu, float& rstd) {
    float s = v, ss = v * v;
#pragma unroll
    for (int off = 32; off; off >>= 1) {
        s  += __shfl_down(s, off);
        ss += __shfl_down(ss, off);
    }
    __shared__ float red[8];
    int wid = threadIdx.x >> 6, lane = threadIdx.x & 63;
    if (lane == 0) { red[wid] = s; red[4 + wid] = ss; }
    __syncthreads();
    float S  = red[0] + red[1] + red[2] + red[3];
    float SS = red[4] + red[5] + red[6] + red[7];
    mu = S * (1.0f / 256.0f);
    float var = SS * (1.0f / 256.0f) - mu * mu;
    rstd = rsqrtf(var + 1e-5f);
}

// LN over all NTOK rows, bf16 out (stride 256)
__global__ __launch_bounds__(256) void ln_bf16_kernel(const float* __restrict__ in,
                                                      u16* __restrict__ outp,
                                                      const float* __restrict__ g,
                                                      const float* __restrict__ bta) {
    int r = blockIdx.x, d = threadIdx.x;
    float v = in[(size_t)r * 256 + d];
    float mu, rstd; ln_stats(v, mu, rstd);
    outp[(size_t)r * 256 + d] = f2bf((v - mu) * rstd * g[d] + bta[d]);
}

// final LN: only carrier rows (b, j<256); writes bf16 into Acat[:, 256:512]
__global__ __launch_bounds__(256) void ln_final_kernel(const float* __restrict__ in,
                                                       u16* __restrict__ Acat,
                                                       const float* __restrict__ g,
                                                       const float* __restrict__ bta) {
    int r = blockIdx.x;                 // 0..16383
    int b = r >> 8, j = r & 255, d = threadIdx.x;
    float v = in[((size_t)b * SEQ + j) * 256 + d];
    float mu, rstd; ln_stats(v, mu, rstd);
    Acat[(size_t)r * 512 + 256 + d] = f2bf((v - mu) * rstd * g[d] + bta[d]);
}

// ---------------- bf16 MFMA GEMM ----------------
// C[M,N] = epi(A[M,K](bf16) @ W[N,K](bf16)^T + bias)   [+ res f32]
// 128x128 tile, BK=32, 256 thr = 4 waves (2x2 of 64x64), double-buffered LDS.
// ACT: 0=none 1=gelu 2=sigmoid ; OUTBF: write bf16 instead of f32.
template <int ACT, int RES, int OUTBF>
__global__ __launch_bounds__(256) void gemm_mfma(const u16* __restrict__ A,
                                                 const u16* __restrict__ W,
                                                 const float* __restrict__ bias,
                                                 const float* __restrict__ res,
                                                 void* __restrict__ Cptr,
                                                 int M, int N, int K) {
    __shared__ u16 lA[2][4][128][8];
    __shared__ u16 lB[2][4][128][8];
    int tid = threadIdx.x;
    int w = tid >> 6, lane = tid & 63;
    int bm = blockIdx.y * 128, bn = blockIdx.x * 128;
    int wr = w >> 1, wc = w & 1;     // 2x2 waves of 64x64

    f32x4 acc[4][4];
#pragma unroll
    for (int r = 0; r < 4; ++r)
#pragma unroll
        for (int c = 0; c < 4; ++c) acc[r][c] = (f32x4){0.f, 0.f, 0.f, 0.f};

    int nt = K / 32;
    // wave w stages kb=w, both row-halves, for A and B
    auto stage = [&](int buf, int t) {
        int k0 = t * 32;
#pragma unroll
        for (int jj = 0; jj < 2; ++jj) {
            int r0 = jj * 64;
            gload16(&A[(size_t)(bm + r0 + lane) * K + k0 + w * 8], &lA[buf][w][r0][0]);
            gload16(&W[(size_t)(bn + r0 + lane) * K + k0 + w * 8], &lB[buf][w][r0][0]);
        }
    };

    stage(0, 0);
    __syncthreads();
    int cur = 0;
    int kb = lane >> 4, rr = lane & 15;
    for (int t = 0; t < nt; ++t) {
        if (t + 1 < nt) stage(cur ^ 1, t + 1);
        short8 af[4], bfv[4];
#pragma unroll
        for (int r = 0; r < 4; ++r)
            af[r] = *(const short8*)&lA[cur][kb][wr * 64 + r * 16 + rr][0];
#pragma unroll
        for (int c = 0; c < 4; ++c)
            bfv[c] = *(const short8*)&lB[cur][kb][wc * 64 + c * 16 + rr][0];
#pragma unroll
        for (int r = 0; r < 4; ++r)
#pragma unroll
            for (int c = 0; c < 4; ++c)
                acc[r][c] = __builtin_amdgcn_mfma_f32_16x16x32_bf16(af[r], bfv[c], acc[r][c], 0, 0, 0);
        __syncthreads();
        cur ^= 1;
    }

    float* Cf = (float*)Cptr;
    u16*   Cb = (u16*)Cptr;
#pragma unroll
    for (int c = 0; c < 4; ++c) {
        int col = bn + wc * 64 + c * 16 + (lane & 15);
        float bia = bias[col];
#pragma unroll
        for (int r = 0; r < 4; ++r) {
#pragma unroll
            for (int j = 0; j < 4; ++j) {
                int row = bm + wr * 64 + r * 16 + (lane >> 4) * 4 + j;
                float v = acc[r][c][j] + bia;
                if (ACT == 1) v = gelu_exact(v);
                if (ACT == 2) v = 1.0f / (1.0f + expf(-v));
                if (RES) v += res[(size_t)row * N + col];
                if (OUTBF) Cb[(size_t)row * N + col] = f2bf(v);
                else       Cf[(size_t)row * N + col] = v;
            }
        }
    }
}

// ---------------- attention (bf16 in/out, fp32 inside) ----------------

__global__ __launch_bounds__(320) void attn_kernel(const u16* __restrict__ qkv,
                                                   u16* __restrict__ o) {
    int b = blockIdx.x >> 3;
    int h = blockIdx.x & 7;
    int r = threadIdx.x;
    const u16* base = qkv + (size_t)b * SEQ * 768;
    const u16* qrow = base + (size_t)r * 768 + h * 32;
    float q[32];
#pragma unroll
    for (int d = 0; d < 32; ++d) q[d] = bf2f(qrow[d]) * 0.17677669529663687f;

    __shared__ float Ks[16][32];
    __shared__ float Vs[16][32];
    float m = -INFINITY, ssum = 0.0f;
    float acc[32];
#pragma unroll
    for (int d = 0; d < 32; ++d) acc[d] = 0.0f;

    for (int k0 = 0; k0 < SEQ; k0 += 16) {
        int t = threadIdx.x;
        if (t < 128) {
            int row = t >> 3, c4 = (t & 7) << 2;
            ushort4 kv = *(const ushort4*)&base[(size_t)(k0 + row) * 768 + 256 + h * 32 + c4];
            Ks[row][c4] = bf2f(kv.x); Ks[row][c4 + 1] = bf2f(kv.y);
            Ks[row][c4 + 2] = bf2f(kv.z); Ks[row][c4 + 3] = bf2f(kv.w);
        } else if (t < 256) {
            int t2 = t - 128;
            int row = t2 >> 3, c4 = (t2 & 7) << 2;
            ushort4 vv = *(const ushort4*)&base[(size_t)(k0 + row) * 768 + 512 + h * 32 + c4];
            Vs[row][c4] = bf2f(vv.x); Vs[row][c4 + 1] = bf2f(vv.y);
            Vs[row][c4 + 2] = bf2f(vv.z); Vs[row][c4 + 3] = bf2f(vv.w);
        }
        __syncthreads();

        float sc[16];
        float cm = -INFINITY;
#pragma unroll
        for (int kk = 0; kk < 16; ++kk) {
            float dot = 0.0f;
#pragma unroll
            for (int d = 0; d < 32; ++d) dot += q[d] * Ks[kk][d];
            sc[kk] = dot;
            cm = fmaxf(cm, dot);
        }
        float nm = fmaxf(m, cm);
        float corr = expf(m - nm);
        ssum *= corr;
#pragma unroll
        for (int d = 0; d < 32; ++d) acc[d] *= corr;
#pragma unroll
        for (int kk = 0; kk < 16; ++kk) {
            float wgt = expf(sc[kk] - nm);
            ssum += wgt;
#pragma unroll
            for (int d = 0; d < 32; ++d) acc[d] += wgt * Vs[kk][d];
        }
        m = nm;
        __syncthreads();
    }
    float inv = 1.0f / ssum;
    u16* orow = o + ((size_t)b * SEQ + r) * 256 + h * 32;
#pragma unroll
    for (int d = 0; d < 32; ++d) orow[d] = f2bf(acc[d] * inv);
}

// ---------------- gate blend + scatter ----------------

__global__ __launch_bounds__(256) void gate_apply_kernel(const float* __restrict__ g,
                                                         const float* __restrict__ h_map,
                                                         const int* __restrict__ idx,
                                                         const u16* __restrict__ Acat,
                                                         float* __restrict__ outp) {
    int b = blockIdx.x >> 8;
    int j = blockIdx.x & 255;
    int d = threadIdx.x;
    int t = idx[j];
    size_t row = (size_t)b * NCV + j;
    float gv = g[row * 256 + d];
    float hv = h_map[((size_t)b * 1089 + t) * 256 + d];
    float nv = bf2f(Acat[row * 512 + 256 + d]);
    outp[((size_t)b * 1089 + t) * 256 + d] = (1.0f - gv) * hv + gv * nv;
}

// ---------------- launch ----------------

extern "C" void kernel_launch(void* const* d_in, const int* in_sizes, int n_in,
                              void* d_out, int out_size, void* d_ws, size_t ws_size,
                              hipStream_t stream) {
    const float* h_map  = (const float*)d_in[0];
    const float* frame  = (const float*)d_in[1];
    const int*   idx    = (const int*)d_in[2];
    const float* Wqkv   = (const float*)d_in[3];
    const float* bqkv   = (const float*)d_in[4];
    const float* Wo     = (const float*)d_in[5];
    const float* bo     = (const float*)d_in[6];
    const float* ln1g   = (const float*)d_in[7];
    const float* ln1b   = (const float*)d_in[8];
    const float* W1     = (const float*)d_in[9];
    const float* b1     = (const float*)d_in[10];
    const float* W2     = (const float*)d_in[11];
    const float* b2     = (const float*)d_in[12];
    const float* ln2g   = (const float*)d_in[13];
    const float* ln2b   = (const float*)d_in[14];
    const float* nfg    = (const float*)d_in[15];
    const float* nfb    = (const float*)d_in[16];
    const float* patchw = (const float*)d_in[17];
    const float* patchb = (const float*)d_in[18];
    const float* gatew  = (const float*)d_in[19];
    const float* gateb  = (const float*)d_in[20];
    float* out = (float*)d_out;

    char* ws = (char*)d_ws;
    size_t off = 0;
    float* x     = (float*)(ws + off); off += (size_t)NTOK * 256 * 4;   // residual stream
    u16*   xbf   = (u16*)(ws + off);   off += (size_t)NTOK * 256 * 2;   // LN out / attn out
    u16*   bigbf = (u16*)(ws + off);   off += (size_t)NTOK * 1024 * 2;  // qkv / mlp hidden
    u16*   Acat  = (u16*)(ws + off);   off += (size_t)NGROW * 512 * 2;  // [h_cv | ln_f]
    float* gbuf  = (float*)(ws + off); off += (size_t)NGROW * 256 * 4;  // sigmoid gates
    u16* wqkvbf  = (u16*)(ws + off);   off += (size_t)6 * 768 * 256 * 2;
    u16* wobf    = (u16*)(ws + off);   off += (size_t)6 * 256 * 256 * 2;
    u16* w1bf    = (u16*)(ws + off);   off += (size_t)6 * 1024 * 256 * 2;
    u16* w2bf    = (u16*)(ws + off);   off += (size_t)6 * 256 * 1024 * 2;
    u16* gwbf    = (u16*)(ws + off);   off += (size_t)256 * 512 * 2;
    u16* pwbf    = (u16*)(ws + off);   off += (size_t)256 * 768 * 2;    // patch_w bf16

    // patch im2col + GEMM scratch: alias into bigbf (unused until layer-0 QKV GEMM)
    float* ptok = (float*)bigbf;                         // [4096][256] f32 (4 MB)
    u16*   pimg = (u16*)(bigbf + (size_t)4096 * 512);    // [4096][768] bf16 (6.3 MB), after ptok

    // weights -> bf16
    hipLaunchKernelGGL(conv_bf16_kernel, dim3(1024), dim3(256), 0, stream, Wqkv, wqkvbf, 6 * 768 * 256);
    hipLaunchKernelGGL(conv_bf16_kernel, dim3(512),  dim3(256), 0, stream, Wo,   wobf,   6 * 256 * 256);
    hipLaunchKernelGGL(conv_bf16_kernel, dim3(1024), dim3(256), 0, stream, W1,   w1bf,   6 * 1024 * 256);
    hipLaunchKernelGGL(conv_bf16_kernel, dim3(1024), dim3(256), 0, stream, W2,   w2bf,   6 * 256 * 1024);
    hipLaunchKernelGGL(conv_bf16_kernel, dim3(128),  dim3(256), 0, stream, gatew, gwbf,  256 * 512);
    hipLaunchKernelGGL(conv_bf16_kernel, dim3(192),  dim3(256), 0, stream, patchw, pwbf, 256 * 768);

    // out = h_map ; build x carrier rows ; Acat left half
    int n4 = (NB * 1089 * 256) / 4;
    hipLaunchKernelGGL(copy_kernel, dim3(2048), dim3(256), 0, stream,
                       (const float4*)h_map, (float4*)out, n4);
    hipLaunchKernelGGL(build_cv_kernel, dim3(NB * 256), dim3(256), 0, stream, h_map, idx, x, Acat);

    // patch embed as GEMM: im2col -> [4096][768] bf16, GEMM -> ptok, scatter+pos -> x
    hipLaunchKernelGGL(im2col_kernel, dim3(NB * 64), dim3(256), 0, stream, frame, pimg);
    hipLaunchKernelGGL((gemm_mfma<0, 0, 0>), dim3(2, 32), dim3(256), 0, stream,
                       pimg, pwbf, patchb, nullptr, ptok, NB * 64, 256, 768);
    hipLaunchKernelGGL(patch_scatter_kernel, dim3(NB * 64), dim3(256), 0, stream, ptok, x);

    for (int l = 0; l < 6; ++l) {
        const u16* wqkv_l = wqkvbf + (size_t)l * 768 * 256;
        const u16* wo_l   = wobf   + (size_t)l * 256 * 256;
        const u16* w1_l   = w1bf   + (size_t)l * 1024 * 256;
        const u16* w2_l   = w2bf   + (size_t)l * 256 * 1024;

        hipLaunchKernelGGL(ln_bf16_kernel, dim3(NTOK), dim3(256), 0, stream,
                           x, xbf, ln1g + l * 256, ln1b + l * 256);
        hipLaunchKernelGGL((gemm_mfma<0, 0, 1>), dim3(6, 160), dim3(256), 0, stream,
                           xbf, wqkv_l, bqkv + l * 768, nullptr, bigbf, NTOK, 768, 256);
        hipLaunchKernelGGL(attn_kernel, dim3(NB * 8), dim3(320), 0, stream, bigbf, xbf);
        hipLaunchKernelGGL((gemm_mfma<0, 1, 0>), dim3(2, 160), dim3(256), 0, stream,
                           xbf, wo_l, bo + l * 256, x, x, NTOK, 256, 256);
        hipLaunchKernelGGL(ln_bf16_kernel, dim3(NTOK), dim3(256), 0, stream,
                           x, xbf, ln2g + l * 256, ln2b + l * 256);
        hipLaunchKernelGGL((gemm_mfma<1, 0, 1>), dim3(8, 160), dim3(256), 0, stream,
                           xbf, w1_l, b1 + l * 1024, nullptr, bigbf, NTOK, 1024, 256);
        hipLaunchKernelGGL((gemm_mfma<0, 1, 0>), dim3(2, 160), dim3(256), 0, stream,
                           bigbf, w2_l, b2 + l * 256, x, x, NTOK, 256, 1024);
    }

    // final LN (carrier rows only) -> Acat right half
    hipLaunchKernelGGL(ln_final_kernel, dim3(NGROW), dim3(256), 0, stream, x, Acat, nfg, nfb);
    // gate GEMM: g = sigmoid(Acat @ gate_w^T + gate_b)
    hipLaunchKernelGGL((gemm_mfma<2, 0, 0>), dim3(2, 128), dim3(256), 0, stream,
                       Acat, gwbf, gateb, nullptr, gbuf, NGROW, 256, 512);
    // blend + scatter
    hipLaunchKernelGGL(gate_apply_kernel, dim3(NB * 256), dim3(256), 0, stream,
                       gbuf, h_map, idx, Acat, out);
}

// Round 13
// 1576.276 us; speedup vs baseline: 5.0825x; 1.3640x over previous
//
#include <hip/hip_runtime.h>
#include <math.h>

#define NB 64
#define SEQ 320
#define NCV 256
#define NTOK (NB * SEQ)    // 20480
#define NGROW (NB * NCV)   // 16384

typedef unsigned short u16;
typedef __attribute__((ext_vector_type(8))) short short8;
typedef __attribute__((ext_vector_type(4))) short short4v;
typedef __attribute__((ext_vector_type(4))) float f32x4;

// ---------------- scalar helpers ----------------

__device__ __forceinline__ float bf2f(u16 u) {
    union { unsigned int i; float f; } v; v.i = ((unsigned int)u) << 16; return v.f;
}
__device__ __forceinline__ u16 f2bf(float f) {
    union { float f; unsigned int i; } v; v.f = f;
    unsigned int lsb = (v.i >> 16) & 1u;
    return (u16)((v.i + 0x7fffu + lsb) >> 16);   // RNE; inputs are finite
}
__device__ __forceinline__ float gelu_exact(float v) {
    return 0.5f * v * (1.0f + erff(v * 0.7071067811865476f));
}
__device__ __forceinline__ float pos2d_val(int yi, int xi, int d) {
    float coord = (float)((d < 128) ? yi : xi);
    int dd = d & 127;
    int i = dd >> 1;
    float freq = expf(-0.14391156831212787f * (float)i);  // 10000^(-2i/128)
    float ang = coord * freq;
    return (dd & 1) ? cosf(ang) : sinf(ang);
}

__device__ __forceinline__ void gload16(const void* g, void* l) {
    __builtin_amdgcn_global_load_lds((const __attribute__((address_space(1))) unsigned int*)g,
                                     (__attribute__((address_space(3))) unsigned int*)l,
                                     16, 0, 0);
}

// ---------------- small kernels ----------------

__global__ __launch_bounds__(256) void conv_bf16_kernel(const float* __restrict__ in,
                                                        u16* __restrict__ outp, int n) {
    int i = blockIdx.x * 256 + threadIdx.x;
    int stride = gridDim.x * 256;
    for (; i < n; i += stride) outp[i] = f2bf(in[i]);
}

__global__ __launch_bounds__(256) void copy_kernel(const float4* __restrict__ src,
                                                   float4* __restrict__ dst, int n4) {
    int i = blockIdx.x * 256 + threadIdx.x;
    int stride = gridDim.x * 256;
    for (; i < n4; i += stride) dst[i] = src[i];
}

// x[b,j,:] = h_map[b,idx[j],:] + pos ;  Acat[b*256+j][0..255] = bf16(h_map val)
__global__ __launch_bounds__(256) void build_cv_kernel(const float* __restrict__ h_map,
                                                       const int* __restrict__ idx,
                                                       float* __restrict__ x,
                                                       u16* __restrict__ Acat) {
    int b = blockIdx.x >> 8;
    int j = blockIdx.x & 255;
    int d = threadIdx.x;
    int t = idx[j];
    int yi = t / 33, xi = t - yi * 33;
    float v = h_map[((size_t)b * 1089 + t) * 256 + d];
    x[((size_t)b * SEQ + j) * 256 + d] = v + pos2d_val(yi, xi, d);
    Acat[((size_t)b * NCV + j) * 512 + d] = f2bf(v);
}

// frame -> bf16 im2col rows [b*64+tok][768], k = c*256 + p*16 + q
__global__ __launch_bounds__(256) void im2col_kernel(const float* __restrict__ frame,
                                                     u16* __restrict__ Abf) {
    int row = blockIdx.x;                 // 0..4095
    int b = row >> 6, tok = row & 63;
    int hh = tok >> 3, ww = tok & 7;
    const float* fb = frame + (size_t)b * 3 * 128 * 128;
    int tid = threadIdx.x;
#pragma unroll
    for (int kk = 0; kk < 3; ++kk) {
        int k = tid + kk * 256;
        int c = k >> 8, rem = k & 255, p = rem >> 4, q = rem & 15;
        float v = fb[c * 16384 + (hh * 16 + p) * 128 + (ww * 16 + q)];
        Abf[(size_t)row * 768 + k] = f2bf(v);
    }
}

// ptok[row][d] + pos2d -> x[b*SEQ+256+tok][d]
__global__ __launch_bounds__(256) void patch_scatter_kernel(const float* __restrict__ ptok,
                                                            float* __restrict__ x) {
    int row = blockIdx.x;                 // 0..4095
    int b = row >> 6, tok = row & 63;
    int d = threadIdx.x;
    float v = ptok[(size_t)row * 256 + d] + pos2d_val(tok >> 3, tok & 7, d);
    x[((size_t)b * SEQ + 256 + tok) * 256 + d] = v;
}

// LN reduce helper: returns (mu, rstd) for value v across the 256-thread block
__device__ __forceinline__ void ln_stats(float v, float& mu, float& rstd) {
    float s = v, ss = v * v;
#pragma unroll
    for (int off = 32; off; off >>= 1) {
        s  += __shfl_down(s, off);
        ss += __shfl_down(ss, off);
    }
    __shared__ float red[8];
    int wid = threadIdx.x >> 6, lane = threadIdx.x & 63;
    if (lane == 0) { red[wid] = s; red[4 + wid] = ss; }
    __syncthreads();
    float S  = red[0] + red[1] + red[2] + red[3];
    float SS = red[4] + red[5] + red[6] + red[7];
    mu = S * (1.0f / 256.0f);
    float var = SS * (1.0f / 256.0f) - mu * mu;
    rstd = rsqrtf(var + 1e-5f);
}

// LN over all NTOK rows, bf16 out (stride 256)
__global__ __launch_bounds__(256) void ln_bf16_kernel(const float* __restrict__ in,
                                                      u16* __restrict__ outp,
                                                      const float* __restrict__ g,
                                                      const float* __restrict__ bta) {
    int r = blockIdx.x, d = threadIdx.x;
    float v = in[(size_t)r * 256 + d];
    float mu, rstd; ln_stats(v, mu, rstd);
    outp[(size_t)r * 256 + d] = f2bf((v - mu) * rstd * g[d] + bta[d]);
}

// final LN: only carrier rows (b, j<256); writes bf16 into Acat[:, 256:512]
__global__ __launch_bounds__(256) void ln_final_kernel(const float* __restrict__ in,
                                                       u16* __restrict__ Acat,
                                                       const float* __restrict__ g,
                                                       const float* __restrict__ bta) {
    int r = blockIdx.x;                 // 0..16383
    int b = r >> 8, j = r & 255, d = threadIdx.x;
    float v = in[((size_t)b * SEQ + j) * 256 + d];
    float mu, rstd; ln_stats(v, mu, rstd);
    Acat[(size_t)r * 512 + 256 + d] = f2bf((v - mu) * rstd * g[d] + bta[d]);
}

// ---------------- bf16 MFMA GEMM ----------------
// C[M,N] = epi(A[M,K](bf16) @ W[N,K](bf16)^T + bias)   [+ res f32]
// 128x128 tile, BK=32, 256 thr = 4 waves (2x2 of 64x64), double-buffered LDS.
// ACT: 0=none 1=gelu 2=sigmoid ; OUTBF: write bf16 instead of f32.
template <int ACT, int RES, int OUTBF>
__global__ __launch_bounds__(256) void gemm_mfma(const u16* __restrict__ A,
                                                 const u16* __restrict__ W,
                                                 const float* __restrict__ bias,
                                                 const float* __restrict__ res,
                                                 void* __restrict__ Cptr,
                                                 int M, int N, int K) {
    __shared__ u16 lA[2][4][128][8];
    __shared__ u16 lB[2][4][128][8];
    int tid = threadIdx.x;
    int w = tid >> 6, lane = tid & 63;
    int bm = blockIdx.y * 128, bn = blockIdx.x * 128;
    int wr = w >> 1, wc = w & 1;     // 2x2 waves of 64x64

    f32x4 acc[4][4];
#pragma unroll
    for (int r = 0; r < 4; ++r)
#pragma unroll
        for (int c = 0; c < 4; ++c) acc[r][c] = (f32x4){0.f, 0.f, 0.f, 0.f};

    int nt = K / 32;
    auto stage = [&](int buf, int t) {
        int k0 = t * 32;
#pragma unroll
        for (int jj = 0; jj < 2; ++jj) {
            int r0 = jj * 64;
            gload16(&A[(size_t)(bm + r0 + lane) * K + k0 + w * 8], &lA[buf][w][r0][0]);
            gload16(&W[(size_t)(bn + r0 + lane) * K + k0 + w * 8], &lB[buf][w][r0][0]);
        }
    };

    stage(0, 0);
    __syncthreads();
    int cur = 0;
    int kb = lane >> 4, rr = lane & 15;
    for (int t = 0; t < nt; ++t) {
        if (t + 1 < nt) stage(cur ^ 1, t + 1);
        short8 af[4], bfv[4];
#pragma unroll
        for (int r = 0; r < 4; ++r)
            af[r] = *(const short8*)&lA[cur][kb][wr * 64 + r * 16 + rr][0];
#pragma unroll
        for (int c = 0; c < 4; ++c)
            bfv[c] = *(const short8*)&lB[cur][kb][wc * 64 + c * 16 + rr][0];
#pragma unroll
        for (int r = 0; r < 4; ++r)
#pragma unroll
            for (int c = 0; c < 4; ++c)
                acc[r][c] = __builtin_amdgcn_mfma_f32_16x16x32_bf16(af[r], bfv[c], acc[r][c], 0, 0, 0);
        __syncthreads();
        cur ^= 1;
    }

    float* Cf = (float*)Cptr;
    u16*   Cb = (u16*)Cptr;
#pragma unroll
    for (int c = 0; c < 4; ++c) {
        int col = bn + wc * 64 + c * 16 + (lane & 15);
        float bia = bias[col];
#pragma unroll
        for (int r = 0; r < 4; ++r) {
#pragma unroll
            for (int j = 0; j < 4; ++j) {
                int row = bm + wr * 64 + r * 16 + (lane >> 4) * 4 + j;
                float v = acc[r][c][j] + bia;
                if (ACT == 1) v = gelu_exact(v);
                if (ACT == 2) v = 1.0f / (1.0f + expf(-v));
                if (RES) v += res[(size_t)row * N + col];
                if (OUTBF) Cb[(size_t)row * N + col] = f2bf(v);
                else       Cf[(size_t)row * N + col] = v;
            }
        }
    }
}

// ---------------- MFMA flash attention ----------------
// One block per (b, h). 4 waves x 80 q-rows. K, V(transposed) staged in LDS.
// Per kv-tile of 32: S = Q K^T (10 MFMAs) -> online softmax -> P (bf16, LDS
// roundtrip, wave-private) -> O += P V (10 MFMAs). Frag layouts identical to
// the verified gemm_mfma patterns.
__global__ __launch_bounds__(256, 2) void attn_mfma_kernel(const u16* __restrict__ qkv,
                                                           u16* __restrict__ o) {
    int b = blockIdx.x >> 3, h = blockIdx.x & 7;
    int tid = threadIdx.x;
    int w = tid >> 6, lane = tid & 63;
    int lo = lane & 15, hi = lane >> 4;

    __shared__ u16 Kl[4][320][8];    // Kl[dblk][kv][i] = K[kv][dblk*8+i]      (20 KB)
    __shared__ u16 Vt[40][32][8];    // Vt[kvb][d][i]  = V[kvb*8+i][d]         (20 KB)
    __shared__ u16 Pl[4][80][36];    // per-wave P rows [q][kv], pad 36        (22.5 KB)

    const u16* base = qkv + (size_t)b * SEQ * 768;

    // stage K + V^T: 1280 (kv,dblk) tasks over 5 iters
    for (int it = 0; it < 5; ++it) {
        int idx = it * 256 + tid;
        int kv = idx >> 2, dblk = idx & 3;
        short8 kvec = *(const short8*)&base[(size_t)kv * 768 + 256 + h * 32 + dblk * 8];
        *(short8*)&Kl[dblk][kv][0] = kvec;
        short8 vvec = *(const short8*)&base[(size_t)kv * 768 + 512 + h * 32 + dblk * 8];
#pragma unroll
        for (int i = 0; i < 8; ++i)
            Vt[kv >> 3][dblk * 8 + i][kv & 7] = (u16)vvec[i];
    }

    // Q fragments: wave w owns rows q0..q0+79
    int q0 = w * 80;
    short8 qf[5];
#pragma unroll
    for (int f = 0; f < 5; ++f)
        qf[f] = *(const short8*)&base[(size_t)(q0 + f * 16 + lo) * 768 + h * 32 + hi * 8];

    __syncthreads();

    float mx[5][4], ls[5][4];
    f32x4 oacc[5][2];
#pragma unroll
    for (int f = 0; f < 5; ++f) {
#pragma unroll
        for (int j = 0; j < 4; ++j) { mx[f][j] = -INFINITY; ls[f][j] = 0.f; }
        oacc[f][0] = (f32x4){0.f, 0.f, 0.f, 0.f};
        oacc[f][1] = (f32x4){0.f, 0.f, 0.f, 0.f};
    }
    const f32x4 zero4 = (f32x4){0.f, 0.f, 0.f, 0.f};
    const float scale = 0.17677669529663687f;  // 1/sqrt(32)

    for (int t = 0; t < 10; ++t) {
        int kv0 = t * 32;
        // S = Q K^T : B-frag = K rows as cols (GEMM W pattern)
        f32x4 s[5][2];
#pragma unroll
        for (int c = 0; c < 2; ++c) {
            short8 kf = *(const short8*)&Kl[hi][kv0 + c * 16 + lo][0];
#pragma unroll
            for (int f = 0; f < 5; ++f)
                s[f][c] = __builtin_amdgcn_mfma_f32_16x16x32_bf16(qf[f], kf, zero4, 0, 0, 0);
        }
        // online softmax: row = f*16 + hi*4 + j lives in lanes {hi*16..hi*16+15}
#pragma unroll
        for (int f = 0; f < 5; ++f) {
#pragma unroll
            for (int j = 0; j < 4; ++j) {
                float s0 = s[f][0][j] * scale, s1 = s[f][1][j] * scale;
                float v = fmaxf(s0, s1);
                v = fmaxf(v, __shfl_xor(v, 1));
                v = fmaxf(v, __shfl_xor(v, 2));
                v = fmaxf(v, __shfl_xor(v, 4));
                v = fmaxf(v, __shfl_xor(v, 8));
                float mn = fmaxf(mx[f][j], v);
                float corr = __expf(mx[f][j] - mn);
                mx[f][j] = mn;
                float p0 = __expf(s0 - mn);
                float p1 = __expf(s1 - mn);
                float ps = p0 + p1;
                ps += __shfl_xor(ps, 1);
                ps += __shfl_xor(ps, 2);
                ps += __shfl_xor(ps, 4);
                ps += __shfl_xor(ps, 8);
                ls[f][j] = ls[f][j] * corr + ps;
                oacc[f][0][j] *= corr;
                oacc[f][1][j] *= corr;
                int q = f * 16 + hi * 4 + j;
                Pl[w][q][lo] = f2bf(p0);
                Pl[w][q][16 + lo] = f2bf(p1);
            }
        }
        // O += P V : A-frag = P rows (GEMM A pattern), B-frag = V^T rows (W pattern)
#pragma unroll
        for (int f = 0; f < 5; ++f) {
            short4v a0 = *(const short4v*)&Pl[w][f * 16 + lo][hi * 8];
            short4v a1 = *(const short4v*)&Pl[w][f * 16 + lo][hi * 8 + 4];
            short8 pa = __builtin_shufflevector(a0, a1, 0, 1, 2, 3, 4, 5, 6, 7);
#pragma unroll
            for (int c = 0; c < 2; ++c) {
                short8 vf = *(const short8*)&Vt[(kv0 >> 3) + hi][c * 16 + lo][0];
                oacc[f][c] = __builtin_amdgcn_mfma_f32_16x16x32_bf16(pa, vf, oacc[f][c], 0, 0, 0);
            }
        }
    }

    // epilogue: O / l -> bf16
#pragma unroll
    for (int f = 0; f < 5; ++f) {
#pragma unroll
        for (int j = 0; j < 4; ++j) {
            float inv = 1.0f / ls[f][j];
            int q = q0 + f * 16 + hi * 4 + j;
#pragma unroll
            for (int c = 0; c < 2; ++c) {
                int d = c * 16 + lo;
                o[(size_t)(b * SEQ + q) * 256 + h * 32 + d] = f2bf(oacc[f][c][j] * inv);
            }
        }
    }
}

// ---------------- gate blend + scatter ----------------

__global__ __launch_bounds__(256) void gate_apply_kernel(const float* __restrict__ g,
                                                         const float* __restrict__ h_map,
                                                         const int* __restrict__ idx,
                                                         const u16* __restrict__ Acat,
                                                         float* __restrict__ outp) {
    int b = blockIdx.x >> 8;
    int j = blockIdx.x & 255;
    int d = threadIdx.x;
    int t = idx[j];
    size_t row = (size_t)b * NCV + j;
    float gv = g[row * 256 + d];
    float hv = h_map[((size_t)b * 1089 + t) * 256 + d];
    float nv = bf2f(Acat[row * 512 + 256 + d]);
    outp[((size_t)b * 1089 + t) * 256 + d] = (1.0f - gv) * hv + gv * nv;
}

// ---------------- launch ----------------

extern "C" void kernel_launch(void* const* d_in, const int* in_sizes, int n_in,
                              void* d_out, int out_size, void* d_ws, size_t ws_size,
                              hipStream_t stream) {
    const float* h_map  = (const float*)d_in[0];
    const float* frame  = (const float*)d_in[1];
    const int*   idx    = (const int*)d_in[2];
    const float* Wqkv   = (const float*)d_in[3];
    const float* bqkv   = (const float*)d_in[4];
    const float* Wo     = (const float*)d_in[5];
    const float* bo     = (const float*)d_in[6];
    const float* ln1g   = (const float*)d_in[7];
    const float* ln1b   = (const float*)d_in[8];
    const float* W1     = (const float*)d_in[9];
    const float* b1     = (const float*)d_in[10];
    const float* W2     = (const float*)d_in[11];
    const float* b2     = (const float*)d_in[12];
    const float* ln2g   = (const float*)d_in[13];
    const float* ln2b   = (const float*)d_in[14];
    const float* nfg    = (const float*)d_in[15];
    const float* nfb    = (const float*)d_in[16];
    const float* patchw = (const float*)d_in[17];
    const float* patchb = (const float*)d_in[18];
    const float* gatew  = (const float*)d_in[19];
    const float* gateb  = (const float*)d_in[20];
    float* out = (float*)d_out;

    char* ws = (char*)d_ws;
    size_t off = 0;
    float* x     = (float*)(ws + off); off += (size_t)NTOK * 256 * 4;   // residual stream
    u16*   xbf   = (u16*)(ws + off);   off += (size_t)NTOK * 256 * 2;   // LN out / attn out
    u16*   bigbf = (u16*)(ws + off);   off += (size_t)NTOK * 1024 * 2;  // qkv / mlp hidden
    u16*   Acat  = (u16*)(ws + off);   off += (size_t)NGROW * 512 * 2;  // [h_cv | ln_f]
    float* gbuf  = (float*)(ws + off); off += (size_t)NGROW * 256 * 4;  // sigmoid gates
    u16* wqkvbf  = (u16*)(ws + off);   off += (size_t)6 * 768 * 256 * 2;
    u16* wobf    = (u16*)(ws + off);   off += (size_t)6 * 256 * 256 * 2;
    u16* w1bf    = (u16*)(ws + off);   off += (size_t)6 * 1024 * 256 * 2;
    u16* w2bf    = (u16*)(ws + off);   off += (size_t)6 * 256 * 1024 * 2;
    u16* gwbf    = (u16*)(ws + off);   off += (size_t)256 * 512 * 2;
    u16* pwbf    = (u16*)(ws + off);   off += (size_t)256 * 768 * 2;    // patch_w bf16

    // patch im2col + GEMM scratch: alias into bigbf (dead before layer-0 QKV GEMM)
    float* ptok = (float*)bigbf;                         // [4096][256] f32
    u16*   pimg = (u16*)(bigbf + (size_t)4096 * 512);    // [4096][768] bf16

    // weights -> bf16
    hipLaunchKernelGGL(conv_bf16_kernel, dim3(1024), dim3(256), 0, stream, Wqkv, wqkvbf, 6 * 768 * 256);
    hipLaunchKernelGGL(conv_bf16_kernel, dim3(512),  dim3(256), 0, stream, Wo,   wobf,   6 * 256 * 256);
    hipLaunchKernelGGL(conv_bf16_kernel, dim3(1024), dim3(256), 0, stream, W1,   w1bf,   6 * 1024 * 256);
    hipLaunchKernelGGL(conv_bf16_kernel, dim3(1024), dim3(256), 0, stream, W2,   w2bf,   6 * 256 * 1024);
    hipLaunchKernelGGL(conv_bf16_kernel, dim3(128),  dim3(256), 0, stream, gatew, gwbf,  256 * 512);
    hipLaunchKernelGGL(conv_bf16_kernel, dim3(192),  dim3(256), 0, stream, patchw, pwbf, 256 * 768);

    // out = h_map ; build x carrier rows ; Acat left half
    int n4 = (NB * 1089 * 256) / 4;
    hipLaunchKernelGGL(copy_kernel, dim3(2048), dim3(256), 0, stream,
                       (const float4*)h_map, (float4*)out, n4);
    hipLaunchKernelGGL(build_cv_kernel, dim3(NB * 256), dim3(256), 0, stream, h_map, idx, x, Acat);

    // patch embed as GEMM
    hipLaunchKernelGGL(im2col_kernel, dim3(NB * 64), dim3(256), 0, stream, frame, pimg);
    hipLaunchKernelGGL((gemm_mfma<0, 0, 0>), dim3(2, 32), dim3(256), 0, stream,
                       pimg, pwbf, patchb, nullptr, ptok, NB * 64, 256, 768);
    hipLaunchKernelGGL(patch_scatter_kernel, dim3(NB * 64), dim3(256), 0, stream, ptok, x);

    for (int l = 0; l < 6; ++l) {
        const u16* wqkv_l = wqkvbf + (size_t)l * 768 * 256;
        const u16* wo_l   = wobf   + (size_t)l * 256 * 256;
        const u16* w1_l   = w1bf   + (size_t)l * 1024 * 256;
        const u16* w2_l   = w2bf   + (size_t)l * 256 * 1024;

        hipLaunchKernelGGL(ln_bf16_kernel, dim3(NTOK), dim3(256), 0, stream,
                           x, xbf, ln1g + l * 256, ln1b + l * 256);
        hipLaunchKernelGGL((gemm_mfma<0, 0, 1>), dim3(6, 160), dim3(256), 0, stream,
                           xbf, wqkv_l, bqkv + l * 768, nullptr, bigbf, NTOK, 768, 256);
        hipLaunchKernelGGL(attn_mfma_kernel, dim3(NB * 8), dim3(256), 0, stream, bigbf, xbf);
        hipLaunchKernelGGL((gemm_mfma<0, 1, 0>), dim3(2, 160), dim3(256), 0, stream,
                           xbf, wo_l, bo + l * 256, x, x, NTOK, 256, 256);
        hipLaunchKernelGGL(ln_bf16_kernel, dim3(NTOK), dim3(256), 0, stream,
                           x, xbf, ln2g + l * 256, ln2b + l * 256);
        hipLaunchKernelGGL((gemm_mfma<1, 0, 1>), dim3(8, 160), dim3(256), 0, stream,
                           xbf, w1_l, b1 + l * 1024, nullptr, bigbf, NTOK, 1024, 256);
        hipLaunchKernelGGL((gemm_mfma<0, 1, 0>), dim3(2, 160), dim3(256), 0, stream,
                           bigbf, w2_l, b2 + l * 256, x, x, NTOK, 256, 1024);
    }

    // final LN (carrier rows only) -> Acat right half
    hipLaunchKernelGGL(ln_final_kernel, dim3(NGROW), dim3(256), 0, stream, x, Acat, nfg, nfb);
    // gate GEMM: g = sigmoid(Acat @ gate_w^T + gate_b)
    hipLaunchKernelGGL((gemm_mfma<2, 0, 0>), dim3(2, 128), dim3(256), 0, stream,
                       Acat, gwbf, gateb, nullptr, gbuf, NGROW, 256, 512);
    // blend + scatter
    hipLaunchKernelGGL(gate_apply_kernel, dim3(NB * 256), dim3(256), 0, stream,
                       gbuf, h_map, idx, Acat, out);
}

// Round 15
// 1538.497 us; speedup vs baseline: 5.2073x; 1.0246x over previous
//
#include <hip/hip_runtime.h>
#include <math.h>

#define NB 64
#define SEQ 320
#define NCV 256
#define NTOK (NB * SEQ)    // 20480
#define NGROW (NB * NCV)   // 16384

typedef unsigned short u16;
typedef __attribute__((ext_vector_type(8))) short short8;
typedef __attribute__((ext_vector_type(4))) short short4v;
typedef __attribute__((ext_vector_type(4))) float f32x4;

// ---------------- scalar helpers ----------------

__device__ __forceinline__ float bf2f(u16 u) {
    union { unsigned int i; float f; } v; v.i = ((unsigned int)u) << 16; return v.f;
}
__device__ __forceinline__ u16 f2bf(float f) {
    union { float f; unsigned int i; } v; v.f = f;
    unsigned int lsb = (v.i >> 16) & 1u;
    return (u16)((v.i + 0x7fffu + lsb) >> 16);   // RNE; inputs are finite
}
__device__ __forceinline__ float gelu_exact(float v) {
    return 0.5f * v * (1.0f + erff(v * 0.7071067811865476f));
}
__device__ __forceinline__ float pos2d_val(int yi, int xi, int d) {
    float coord = (float)((d < 128) ? yi : xi);
    int dd = d & 127;
    int i = dd >> 1;
    float freq = expf(-0.14391156831212787f * (float)i);  // 10000^(-2i/128)
    float ang = coord * freq;
    return (dd & 1) ? cosf(ang) : sinf(ang);
}

__device__ __forceinline__ void gload16(const void* g, void* l) {
    __builtin_amdgcn_global_load_lds((const __attribute__((address_space(1))) unsigned int*)g,
                                     (__attribute__((address_space(3))) unsigned int*)l,
                                     16, 0, 0);
}

// ---------------- small kernels ----------------

__global__ __launch_bounds__(256) void conv_bf16_kernel(const float* __restrict__ in,
                                                        u16* __restrict__ outp, int n) {
    int i = blockIdx.x * 256 + threadIdx.x;
    int stride = gridDim.x * 256;
    for (; i < n; i += stride) outp[i] = f2bf(in[i]);
}

__global__ __launch_bounds__(256) void copy_kernel(const float4* __restrict__ src,
                                                   float4* __restrict__ dst, int n4) {
    int i = blockIdx.x * 256 + threadIdx.x;
    int stride = gridDim.x * 256;
    for (; i < n4; i += stride) dst[i] = src[i];
}

// x[b,j,:] = h_map[b,idx[j],:] + pos ;  Acat[b*256+j][0..255] = bf16(h_map val)
__global__ __launch_bounds__(256) void build_cv_kernel(const float* __restrict__ h_map,
                                                       const int* __restrict__ idx,
                                                       float* __restrict__ x,
                                                       u16* __restrict__ Acat) {
    int b = blockIdx.x >> 8;
    int j = blockIdx.x & 255;
    int d = threadIdx.x;
    int t = idx[j];
    int yi = t / 33, xi = t - yi * 33;
    float v = h_map[((size_t)b * 1089 + t) * 256 + d];
    x[((size_t)b * SEQ + j) * 256 + d] = v + pos2d_val(yi, xi, d);
    Acat[((size_t)b * NCV + j) * 512 + d] = f2bf(v);
}

// frame -> bf16 im2col rows [b*64+tok][768], k = c*256 + p*16 + q
__global__ __launch_bounds__(256) void im2col_kernel(const float* __restrict__ frame,
                                                     u16* __restrict__ Abf) {
    int row = blockIdx.x;                 // 0..4095
    int b = row >> 6, tok = row & 63;
    int hh = tok >> 3, ww = tok & 7;
    const float* fb = frame + (size_t)b * 3 * 128 * 128;
    int tid = threadIdx.x;
#pragma unroll
    for (int kk = 0; kk < 3; ++kk) {
        int k = tid + kk * 256;
        int c = k >> 8, rem = k & 255, p = rem >> 4, q = rem & 15;
        float v = fb[c * 16384 + (hh * 16 + p) * 128 + (ww * 16 + q)];
        Abf[(size_t)row * 768 + k] = f2bf(v);
    }
}

// ptok[row][d] + pos2d -> x[b*SEQ+256+tok][d]
__global__ __launch_bounds__(256) void patch_scatter_kernel(const float* __restrict__ ptok,
                                                            float* __restrict__ x) {
    int row = blockIdx.x;                 // 0..4095
    int b = row >> 6, tok = row & 63;
    int d = threadIdx.x;
    float v = ptok[(size_t)row * 256 + d] + pos2d_val(tok >> 3, tok & 7, d);
    x[((size_t)b * SEQ + 256 + tok) * 256 + d] = v;
}

// LN reduce helper: returns (mu, rstd) for value v across the 256-thread block
__device__ __forceinline__ void ln_stats(float v, float& mu, float& rstd) {
    float s = v, ss = v * v;
#pragma unroll
    for (int off = 32; off; off >>= 1) {
        s  += __shfl_down(s, off);
        ss += __shfl_down(ss, off);
    }
    __shared__ float red[8];
    int wid = threadIdx.x >> 6, lane = threadIdx.x & 63;
    if (lane == 0) { red[wid] = s; red[4 + wid] = ss; }
    __syncthreads();
    float S  = red[0] + red[1] + red[2] + red[3];
    float SS = red[4] + red[5] + red[6] + red[7];
    mu = S * (1.0f / 256.0f);
    float var = SS * (1.0f / 256.0f) - mu * mu;
    rstd = rsqrtf(var + 1e-5f);
}

// LN over all NTOK rows, bf16 out (stride 256)
__global__ __launch_bounds__(256) void ln_bf16_kernel(const float* __restrict__ in,
                                                      u16* __restrict__ outp,
                                                      const float* __restrict__ g,
                                                      const float* __restrict__ bta) {
    int r = blockIdx.x, d = threadIdx.x;
    float v = in[(size_t)r * 256 + d];
    float mu, rstd; ln_stats(v, mu, rstd);
    outp[(size_t)r * 256 + d] = f2bf((v - mu) * rstd * g[d] + bta[d]);
}

// final LN: only carrier rows (b, j<256); writes bf16 into Acat[:, 256:512]
__global__ __launch_bounds__(256) void ln_final_kernel(const float* __restrict__ in,
                                                       u16* __restrict__ Acat,
                                                       const float* __restrict__ g,
                                                       const float* __restrict__ bta) {
    int r = blockIdx.x;                 // 0..16383
    int b = r >> 8, j = r & 255, d = threadIdx.x;
    float v = in[((size_t)b * SEQ + j) * 256 + d];
    float mu, rstd; ln_stats(v, mu, rstd);
    Acat[(size_t)r * 512 + 256 + d] = f2bf((v - mu) * rstd * g[d] + bta[d]);
}

// ---------------- bf16 MFMA GEMM ----------------
// C[M,N] = epi(A[M,K](bf16) @ W[N,K](bf16)^T + bias)   [+ res f32]
// 128x128 tile, BK=32, 256 thr = 4 waves (2x2 of 64x64), double-buffered LDS.
// MFMA operands SWAPPED (W-frag as arg0, token-frag as arg1) so the C/D
// fragment holds 4 consecutive FEATURES per lane -> float4/ushort4 stores.
// ACT: 0=none 1=gelu 2=sigmoid ; OUTBF: write bf16 instead of f32.
template <int ACT, int RES, int OUTBF>
__global__ __launch_bounds__(256) void gemm_mfma(const u16* __restrict__ A,
                                                 const u16* __restrict__ W,
                                                 const float* __restrict__ bias,
                                                 const float* __restrict__ res,
                                                 void* __restrict__ Cptr,
                                                 int M, int N, int K) {
    __shared__ u16 lA[2][4][128][8];
    __shared__ u16 lB[2][4][128][8];
    int tid = threadIdx.x;
    int w = tid >> 6, lane = tid & 63;
    int bm = blockIdx.y * 128, bn = blockIdx.x * 128;
    int wr = w >> 1, wc = w & 1;     // 2x2 waves of 64x64

    f32x4 acc[4][4];
#pragma unroll
    for (int r = 0; r < 4; ++r)
#pragma unroll
        for (int c = 0; c < 4; ++c) acc[r][c] = (f32x4){0.f, 0.f, 0.f, 0.f};

    int nt = K / 32;
    auto stage = [&](int buf, int t) {
        int k0 = t * 32;
#pragma unroll
        for (int jj = 0; jj < 2; ++jj) {
            int r0 = jj * 64;
            gload16(&A[(size_t)(bm + r0 + lane) * K + k0 + w * 8], &lA[buf][w][r0][0]);
            gload16(&W[(size_t)(bn + r0 + lane) * K + k0 + w * 8], &lB[buf][w][r0][0]);
        }
    };

    stage(0, 0);
    __syncthreads();
    int cur = 0;
    int kb = lane >> 4, rr = lane & 15;
    for (int t = 0; t < nt; ++t) {
        if (t + 1 < nt) stage(cur ^ 1, t + 1);
        short8 af[4], bfv[4];
#pragma unroll
        for (int r = 0; r < 4; ++r)
            af[r] = *(const short8*)&lA[cur][kb][wr * 64 + r * 16 + rr][0];
#pragma unroll
        for (int c = 0; c < 4; ++c)
            bfv[c] = *(const short8*)&lB[cur][kb][wc * 64 + c * 16 + rr][0];
#pragma unroll
        for (int r = 0; r < 4; ++r)
#pragma unroll
            for (int c = 0; c < 4; ++c)
                acc[r][c] = __builtin_amdgcn_mfma_f32_16x16x32_bf16(bfv[c], af[r], acc[r][c], 0, 0, 0);
        __syncthreads();
        cur ^= 1;
    }

    // epilogue: lane holds token row = ...+rr, features colb..colb+3 (regs j)
    float* Cf = (float*)Cptr;
    u16*   Cb = (u16*)Cptr;
#pragma unroll
    for (int r = 0; r < 4; ++r) {
        int row = bm + wr * 64 + r * 16 + rr;
#pragma unroll
        for (int c = 0; c < 4; ++c) {
            int colb = bn + wc * 64 + c * 16 + kb * 4;
            const float4 bia = *(const float4*)&bias[colb];
            float vj[4] = {acc[r][c][0] + bia.x, acc[r][c][1] + bia.y,
                           acc[r][c][2] + bia.z, acc[r][c][3] + bia.w};
#pragma unroll
            for (int j = 0; j < 4; ++j) {
                if (ACT == 1) vj[j] = gelu_exact(vj[j]);
                if (ACT == 2) vj[j] = 1.0f / (1.0f + expf(-vj[j]));
            }
            if (RES) {
                const float4 rr4 = *(const float4*)&res[(size_t)row * N + colb];
                vj[0] += rr4.x; vj[1] += rr4.y; vj[2] += rr4.z; vj[3] += rr4.w;
            }
            if (OUTBF) {
                ushort4 st = { f2bf(vj[0]), f2bf(vj[1]), f2bf(vj[2]), f2bf(vj[3]) };
                *(ushort4*)&Cb[(size_t)row * N + colb] = st;
            } else {
                float4 st = { vj[0], vj[1], vj[2], vj[3] };
                *(float4*)&Cf[(size_t)row * N + colb] = st;
            }
        }
    }
}

// ---------------- MFMA flash attention ----------------
// One block per (b, h). 4 waves x 80 q-rows. Deferred lane-partial softmax
// sum (reduced once in epilogue); max still shfl-reduced per tile.
__global__ __launch_bounds__(256, 2) void attn_mfma_kernel(const u16* __restrict__ qkv,
                                                           u16* __restrict__ o) {
    int b = blockIdx.x >> 3, h = blockIdx.x & 7;
    int tid = threadIdx.x;
    int w = tid >> 6, lane = tid & 63;
    int lo = lane & 15, hi = lane >> 4;

    __shared__ u16 Kl[4][320][8];    // Kl[dblk][kv][i] = K[kv][dblk*8+i]      (20 KB)
    __shared__ u16 Vt[40][32][8];    // Vt[kvb][d][i]  = V[kvb*8+i][d]         (20 KB)
    __shared__ u16 Pl[4][80][36];    // per-wave P rows [q][kv], pad 36        (22.5 KB)

    const u16* base = qkv + (size_t)b * SEQ * 768;

    for (int it = 0; it < 5; ++it) {
        int idx = it * 256 + tid;
        int kv = idx >> 2, dblk = idx & 3;
        short8 kvec = *(const short8*)&base[(size_t)kv * 768 + 256 + h * 32 + dblk * 8];
        *(short8*)&Kl[dblk][kv][0] = kvec;
        short8 vvec = *(const short8*)&base[(size_t)kv * 768 + 512 + h * 32 + dblk * 8];
#pragma unroll
        for (int i = 0; i < 8; ++i)
            Vt[kv >> 3][dblk * 8 + i][kv & 7] = (u16)vvec[i];
    }

    int q0 = w * 80;
    short8 qf[5];
#pragma unroll
    for (int f = 0; f < 5; ++f)
        qf[f] = *(const short8*)&base[(size_t)(q0 + f * 16 + lo) * 768 + h * 32 + hi * 8];

    __syncthreads();

    float mx[5][4], lsl[5][4];       // lsl = LANE-PARTIAL exp-sum
    f32x4 oacc[5][2];
#pragma unroll
    for (int f = 0; f < 5; ++f) {
#pragma unroll
        for (int j = 0; j < 4; ++j) { mx[f][j] = -INFINITY; lsl[f][j] = 0.f; }
        oacc[f][0] = (f32x4){0.f, 0.f, 0.f, 0.f};
        oacc[f][1] = (f32x4){0.f, 0.f, 0.f, 0.f};
    }
    const f32x4 zero4 = (f32x4){0.f, 0.f, 0.f, 0.f};
    const float scale = 0.17677669529663687f;  // 1/sqrt(32)

    for (int t = 0; t < 10; ++t) {
        int kv0 = t * 32;
        f32x4 s[5][2];
#pragma unroll
        for (int c = 0; c < 2; ++c) {
            short8 kf = *(const short8*)&Kl[hi][kv0 + c * 16 + lo][0];
#pragma unroll
            for (int f = 0; f < 5; ++f)
                s[f][c] = __builtin_amdgcn_mfma_f32_16x16x32_bf16(qf[f], kf, zero4, 0, 0, 0);
        }
#pragma unroll
        for (int f = 0; f < 5; ++f) {
#pragma unroll
            for (int j = 0; j < 4; ++j) {
                float s0 = s[f][0][j] * scale, s1 = s[f][1][j] * scale;
                float v = fmaxf(s0, s1);
                v = fmaxf(v, __shfl_xor(v, 1));
                v = fmaxf(v, __shfl_xor(v, 2));
                v = fmaxf(v, __shfl_xor(v, 4));
                v = fmaxf(v, __shfl_xor(v, 8));
                float mn = fmaxf(mx[f][j], v);
                float corr = __expf(mx[f][j] - mn);   // row-uniform across the 16 lanes
                mx[f][j] = mn;
                float p0 = __expf(s0 - mn);
                float p1 = __expf(s1 - mn);
                lsl[f][j] = lsl[f][j] * corr + (p0 + p1);   // lane-partial, no shfl
                oacc[f][0][j] *= corr;
                oacc[f][1][j] *= corr;
                int q = f * 16 + hi * 4 + j;
                Pl[w][q][lo] = f2bf(p0);
                Pl[w][q][16 + lo] = f2bf(p1);
            }
        }
#pragma unroll
        for (int f = 0; f < 5; ++f) {
            short4v a0 = *(const short4v*)&Pl[w][f * 16 + lo][hi * 8];
            short4v a1 = *(const short4v*)&Pl[w][f * 16 + lo][hi * 8 + 4];
            short8 pa = __builtin_shufflevector(a0, a1, 0, 1, 2, 3, 4, 5, 6, 7);
#pragma unroll
            for (int c = 0; c < 2; ++c) {
                short8 vf = *(const short8*)&Vt[(kv0 >> 3) + hi][c * 16 + lo][0];
                oacc[f][c] = __builtin_amdgcn_mfma_f32_16x16x32_bf16(pa, vf, oacc[f][c], 0, 0, 0);
            }
        }
    }

    // epilogue: reduce lane-partial sums once, then O / l -> bf16
#pragma unroll
    for (int f = 0; f < 5; ++f) {
#pragma unroll
        for (int j = 0; j < 4; ++j) {
            float ps = lsl[f][j];
            ps += __shfl_xor(ps, 1);
            ps += __shfl_xor(ps, 2);
            ps += __shfl_xor(ps, 4);
            ps += __shfl_xor(ps, 8);
            float inv = 1.0f / ps;
            int q = q0 + f * 16 + hi * 4 + j;
#pragma unroll
            for (int c = 0; c < 2; ++c) {
                int d = c * 16 + lo;
                o[(size_t)(b * SEQ + q) * 256 + h * 32 + d] = f2bf(oacc[f][c][j] * inv);
            }
        }
    }
}

// ---------------- gate blend + scatter ----------------

__global__ __launch_bounds__(256) void gate_apply_kernel(const float* __restrict__ g,
                                                         const float* __restrict__ h_map,
                                                         const int* __restrict__ idx,
                                                         const u16* __restrict__ Acat,
                                                         float* __restrict__ outp) {
    int b = blockIdx.x >> 8;
    int j = blockIdx.x & 255;
    int d = threadIdx.x;
    int t = idx[j];
    size_t row = (size_t)b * NCV + j;
    float gv = g[row * 256 + d];
    float hv = h_map[((size_t)b * 1089 + t) * 256 + d];
    float nv = bf2f(Acat[row * 512 + 256 + d]);
    outp[((size_t)b * 1089 + t) * 256 + d] = (1.0f - gv) * hv + gv * nv;
}

// ---------------- launch ----------------

extern "C" void kernel_launch(void* const* d_in, const int* in_sizes, int n_in,
                              void* d_out, int out_size, void* d_ws, size_t ws_size,
                              hipStream_t stream) {
    const float* h_map  = (const float*)d_in[0];
    const float* frame  = (const float*)d_in[1];
    const int*   idx    = (const int*)d_in[2];
    const float* Wqkv   = (const float*)d_in[3];
    const float* bqkv   = (const float*)d_in[4];
    const float* Wo     = (const float*)d_in[5];
    const float* bo     = (const float*)d_in[6];
    const float* ln1g   = (const float*)d_in[7];
    const float* ln1b   = (const float*)d_in[8];
    const float* W1     = (const float*)d_in[9];
    const float* b1     = (const float*)d_in[10];
    const float* W2     = (const float*)d_in[11];
    const float* b2     = (const float*)d_in[12];
    const float* ln2g   = (const float*)d_in[13];
    const float* ln2b   = (const float*)d_in[14];
    const float* nfg    = (const float*)d_in[15];
    const float* nfb    = (const float*)d_in[16];
    const float* patchw = (const float*)d_in[17];
    const float* patchb = (const float*)d_in[18];
    const float* gatew  = (const float*)d_in[19];
    const float* gateb  = (const float*)d_in[20];
    float* out = (float*)d_out;

    char* ws = (char*)d_ws;
    size_t off = 0;
    float* x     = (float*)(ws + off); off += (size_t)NTOK * 256 * 4;   // residual stream
    u16*   xbf   = (u16*)(ws + off);   off += (size_t)NTOK * 256 * 2;   // LN out / attn out
    u16*   bigbf = (u16*)(ws + off);   off += (size_t)NTOK * 1024 * 2;  // qkv / mlp hidden
    u16*   Acat  = (u16*)(ws + off);   off += (size_t)NGROW * 512 * 2;  // [h_cv | ln_f]
    float* gbuf  = (float*)(ws + off); off += (size_t)NGROW * 256 * 4;  // sigmoid gates
    u16* wqkvbf  = (u16*)(ws + off);   off += (size_t)6 * 768 * 256 * 2;
    u16* wobf    = (u16*)(ws + off);   off += (size_t)6 * 256 * 256 * 2;
    u16* w1bf    = (u16*)(ws + off);   off += (size_t)6 * 1024 * 256 * 2;
    u16* w2bf    = (u16*)(ws + off);   off += (size_t)6 * 256 * 1024 * 2;
    u16* gwbf    = (u16*)(ws + off);   off += (size_t)256 * 512 * 2;
    u16* pwbf    = (u16*)(ws + off);   off += (size_t)256 * 768 * 2;    // patch_w bf16

    // patch im2col + GEMM scratch: alias into bigbf (dead before layer-0 QKV GEMM)
    float* ptok = (float*)bigbf;                         // [4096][256] f32
    u16*   pimg = (u16*)(bigbf + (size_t)4096 * 512);    // [4096][768] bf16

    // weights -> bf16
    hipLaunchKernelGGL(conv_bf16_kernel, dim3(1024), dim3(256), 0, stream, Wqkv, wqkvbf, 6 * 768 * 256);
    hipLaunchKernelGGL(conv_bf16_kernel, dim3(512),  dim3(256), 0, stream, Wo,   wobf,   6 * 256 * 256);
    hipLaunchKernelGGL(conv_bf16_kernel, dim3(1024), dim3(256), 0, stream, W1,   w1bf,   6 * 1024 * 256);
    hipLaunchKernelGGL(conv_bf16_kernel, dim3(1024), dim3(256), 0, stream, W2,   w2bf,   6 * 256 * 1024);
    hipLaunchKernelGGL(conv_bf16_kernel, dim3(128),  dim3(256), 0, stream, gatew, gwbf,  256 * 512);
    hipLaunchKernelGGL(conv_bf16_kernel, dim3(192),  dim3(256), 0, stream, patchw, pwbf, 256 * 768);

    // out = h_map ; build x carrier rows ; Acat left half
    int n4 = (NB * 1089 * 256) / 4;
    hipLaunchKernelGGL(copy_kernel, dim3(2048), dim3(256), 0, stream,
                       (const float4*)h_map, (float4*)out, n4);
    hipLaunchKernelGGL(build_cv_kernel, dim3(NB * 256), dim3(256), 0, stream, h_map, idx, x, Acat);

    // patch embed as GEMM
    hipLaunchKernelGGL(im2col_kernel, dim3(NB * 64), dim3(256), 0, stream, frame, pimg);
    hipLaunchKernelGGL((gemm_mfma<0, 0, 0>), dim3(2, 32), dim3(256), 0, stream,
                       pimg, pwbf, patchb, nullptr, ptok, NB * 64, 256, 768);
    hipLaunchKernelGGL(patch_scatter_kernel, dim3(NB * 64), dim3(256), 0, stream, ptok, x);

    for (int l = 0; l < 6; ++l) {
        const u16* wqkv_l = wqkvbf + (size_t)l * 768 * 256;
        const u16* wo_l   = wobf   + (size_t)l * 256 * 256;
        const u16* w1_l   = w1bf   + (size_t)l * 1024 * 256;
        const u16* w2_l   = w2bf   + (size_t)l * 256 * 1024;

        hipLaunchKernelGGL(ln_bf16_kernel, dim3(NTOK), dim3(256), 0, stream,
                           x, xbf, ln1g + l * 256, ln1b + l * 256);
        hipLaunchKernelGGL((gemm_mfma<0, 0, 1>), dim3(6, 160), dim3(256), 0, stream,
                           xbf, wqkv_l, bqkv + l * 768, nullptr, bigbf, NTOK, 768, 256);
        hipLaunchKernelGGL(attn_mfma_kernel, dim3(NB * 8), dim3(256), 0, stream, bigbf, xbf);
        hipLaunchKernelGGL((gemm_mfma<0, 1, 0>), dim3(2, 160), dim3(256), 0, stream,
                           xbf, wo_l, bo + l * 256, x, x, NTOK, 256, 256);
        hipLaunchKernelGGL(ln_bf16_kernel, dim3(NTOK), dim3(256), 0, stream,
                           x, xbf, ln2g + l * 256, ln2b + l * 256);
        hipLaunchKernelGGL((gemm_mfma<1, 0, 1>), dim3(8, 160), dim3(256), 0, stream,
                           xbf, w1_l, b1 + l * 1024, nullptr, bigbf, NTOK, 1024, 256);
        hipLaunchKernelGGL((gemm_mfma<0, 1, 0>), dim3(2, 160), dim3(256), 0, stream,
                           bigbf, w2_l, b2 + l * 256, x, x, NTOK, 256, 1024);
    }

    // final LN (carrier rows only) -> Acat right half
    hipLaunchKernelGGL(ln_final_kernel, dim3(NGROW), dim3(256), 0, stream, x, Acat, nfg, nfb);
    // gate GEMM: g = sigmoid(Acat @ gate_w^T + gate_b)
    hipLaunchKernelGGL((gemm_mfma<2, 0, 0>), dim3(2, 128), dim3(256), 0, stream,
                       Acat, gwbf, gateb, nullptr, gbuf, NGROW, 256, 512);
    // blend + scatter
    hipLaunchKernelGGL(gate_apply_kernel, dim3(NB * 256), dim3(256), 0, stream,
                       gbuf, h_map, idx, Acat, out);
}